// Round 1
// baseline (3007.702 us; speedup 1.0000x reference)
//
#include <hip/hip_runtime.h>
#include <hip/hip_bf16.h>
#include <math.h>

// ---- problem constants ----
#define BATCH 4
#define CCH   192
#define HH    56
#define WW    56
#define LSEQ  (HH*WW)          // 3136
#define NTOK  (BATCH*LSEQ)     // 12544
#define DST   16               // D_STATE
#define DIN   384              // D_INNER
#define DTR   12               // DT_RANK
#define XDM   (DTR + 2*DST)    // 44

__device__ __forceinline__ float siluf(float x)  { return x / (1.f + __expf(-x)); }
__device__ __forceinline__ float geluf(float x)  { return 0.5f * x * (1.f + erff(x * 0.70710678118654752f)); }
__device__ __forceinline__ float softplusf(float x) { return (x > 20.f) ? x : log1pf(__expf(x)); }

// ---------------- LayerNorm over C, NCHW input -> (B*L, C) tokens ----------------
// one wave (64 lanes) per token row; each lane handles 3 channels
__global__ __launch_bounds__(256) void ln_kernel(const float* __restrict__ x,
                                                 const float* __restrict__ g,
                                                 const float* __restrict__ bta,
                                                 float* __restrict__ out) {
    int row  = blockIdx.x * 4 + (threadIdx.x >> 6);
    int lane = threadIdx.x & 63;
    if (row >= NTOK) return;
    int b  = row / LSEQ;
    int hw = row % LSEQ;
    const float* xp = x + (size_t)b * CCH * LSEQ + hw;
    float v[3];
    float s = 0.f, s2 = 0.f;
#pragma unroll
    for (int i = 0; i < 3; i++) {
        int c = lane + i * 64;
        float val = xp[(size_t)c * LSEQ];
        v[i] = val; s += val; s2 += val * val;
    }
#pragma unroll
    for (int m = 32; m >= 1; m >>= 1) { s += __shfl_xor(s, m); s2 += __shfl_xor(s2, m); }
    float mean = s * (1.f / CCH);
    float var  = s2 * (1.f / CCH) - mean * mean;
    float rstd = rsqrtf(var + 1e-5f);
    float* op = out + (size_t)row * CCH;
#pragma unroll
    for (int i = 0; i < 3; i++) {
        int c = lane + i * 64;
        op[c] = (v[i] - mean) * rstd * g[c] + bta[c];
    }
}

// ---------------- generic fp32 GEMM: C[M,N] = A[M,K(lda)] * W[N,K]^T ----------------
// EPI: 0=none, 1=bias+softplus, 2=bias+gelu
template<int EPI>
__global__ __launch_bounds__(256) void gemm_nt(const float* __restrict__ A, int lda,
                                               const float* __restrict__ Wt,
                                               const float* __restrict__ bias,
                                               float* __restrict__ Cout,
                                               int M, int N, int K) {
    __shared__ float As[16][64 + 1];
    __shared__ float Ws[16][64 + 1];
    int tid = threadIdx.x;
    int bm = blockIdx.y * 64;
    int bn = blockIdx.x * 64;
    int lr = tid >> 4;          // 0..15
    int lk = tid & 15;          // 0..15
    int tm = (tid >> 4) << 2;   // 0..60
    int tn = (tid & 15) << 2;   // 0..60
    float acc[4][4] = {};
    for (int k0 = 0; k0 < K; k0 += 16) {
#pragma unroll
        for (int p = 0; p < 4; p++) {
            int m = bm + lr + 16 * p;
            int k = k0 + lk;
            float v = 0.f;
            if (m < M && k < K) v = A[(size_t)m * lda + k];
            As[lk][lr + 16 * p] = v;
        }
#pragma unroll
        for (int p = 0; p < 4; p++) {
            int n = bn + lr + 16 * p;
            int k = k0 + lk;
            float v = 0.f;
            if (n < N && k < K) v = Wt[(size_t)n * K + k];
            Ws[lk][lr + 16 * p] = v;
        }
        __syncthreads();
#pragma unroll
        for (int kk = 0; kk < 16; kk++) {
            float a[4], w[4];
#pragma unroll
            for (int i = 0; i < 4; i++) a[i] = As[kk][tm + i];
#pragma unroll
            for (int j = 0; j < 4; j++) w[j] = Ws[kk][tn + j];
#pragma unroll
            for (int i = 0; i < 4; i++)
#pragma unroll
                for (int j = 0; j < 4; j++)
                    acc[i][j] += a[i] * w[j];
        }
        __syncthreads();
    }
#pragma unroll
    for (int i = 0; i < 4; i++) {
        int m = bm + tm + i;
        if (m >= M) continue;
#pragma unroll
        for (int j = 0; j < 4; j++) {
            int n = bn + tn + j;
            if (n >= N) continue;
            float v = acc[i][j];
            if (EPI == 1) { v += bias[n]; v = softplusf(v); }
            else if (EPI == 2) { v += bias[n]; v = geluf(v); }
            Cout[(size_t)m * N + n] = v;
        }
    }
}

// ---------------- causal depthwise conv1d (k=3) + SiLU ----------------
// reads xm part of xz (cols 0..DIN-1 of 2*DIN), writes xm_act (NTOK x DIN)
__global__ __launch_bounds__(256) void conv1d_silu(const float* __restrict__ xz,
                                                   const float* __restrict__ w,
                                                   const float* __restrict__ bias,
                                                   float* __restrict__ out) {
    int idx = blockIdx.x * 256 + threadIdx.x;
    if (idx >= NTOK * DIN) return;
    int m = idx / DIN, d = idx % DIN;
    int l = m % LSEQ;
    float w0 = w[d * 3 + 0], w1 = w[d * 3 + 1], w2 = w[d * 3 + 2];
    float acc = bias[d] + w2 * xz[(size_t)m * (2 * DIN) + d];
    if (l >= 1) acc += w1 * xz[(size_t)(m - 1) * (2 * DIN) + d];
    if (l >= 2) acc += w0 * xz[(size_t)(m - 2) * (2 * DIN) + d];
    out[idx] = siluf(acc);
}

// ---------------- selective scan ----------------
// 16 lanes per (b,d) pair: lane n holds state h_n; shuffle-reduce for y.
__global__ __launch_bounds__(256) void scan_kernel(const float* __restrict__ delta,
                                                   const float* __restrict__ xm,
                                                   const float* __restrict__ xdbl,
                                                   const float* __restrict__ xz,
                                                   const float* __restrict__ A_log,
                                                   const float* __restrict__ Dskip,
                                                   float* __restrict__ ybuf) {
    int t = blockIdx.x * 256 + threadIdx.x;
    int pair = t >> 4;
    int n = t & 15;
    if (pair >= BATCH * DIN) return;
    int b = pair / DIN;
    int d = pair % DIN;
    float An = -__expf(A_log[d * DST + n]);
    float Dv = Dskip[d];
    float h = 0.f;
    for (int l = 0; l < LSEQ; l++) {
        int m = b * LSEQ + l;
        float dlt = delta[(size_t)m * DIN + d];
        float xv  = xm[(size_t)m * DIN + d];
        float Bv  = xdbl[(size_t)m * XDM + DTR + n];
        float Cv  = xdbl[(size_t)m * XDM + DTR + DST + n];
        float dA = __expf(dlt * An);
        h = dA * h + (dlt * xv) * Bv;
        float yp = h * Cv;
        yp += __shfl_xor(yp, 1);
        yp += __shfl_xor(yp, 2);
        yp += __shfl_xor(yp, 4);
        yp += __shfl_xor(yp, 8);
        if (n == 0) {
            float zv = xz[(size_t)m * (2 * DIN) + DIN + d];
            ybuf[(size_t)m * DIN + d] = (yp + xv * Dv) * siluf(zv);
        }
    }
}

// ---------------- x1 = x + transpose(mamba_out) ----------------
__global__ __launch_bounds__(256) void add_tr(const float* __restrict__ x,
                                              const float* __restrict__ mo,
                                              float* __restrict__ x1) {
    int idx = blockIdx.x * 256 + threadIdx.x;
    if (idx >= NTOK * CCH) return;
    int w = idx % WW; int tmp = idx / WW;
    int h = tmp % HH; tmp /= HH;
    int c = tmp % CCH; int b = tmp / CCH;
    int m = b * LSEQ + h * WW + w;
    x1[idx] = x[idx] + mo[(size_t)m * CCH + c];
}

// ---------------- depthwise 3x3 conv + BN + GELU + residual ----------------
__global__ __launch_bounds__(256) void dwconv_bn_gelu(const float* __restrict__ x1,
                                                      const float* __restrict__ wdw,
                                                      const float* __restrict__ bn_g,
                                                      const float* __restrict__ bn_b,
                                                      const float* __restrict__ bn_mean,
                                                      const float* __restrict__ bn_var,
                                                      float* __restrict__ x2) {
    int idx = blockIdx.x * 256 + threadIdx.x;
    if (idx >= NTOK * CCH) return;
    int w = idx % WW; int tmp = idx / WW;
    int h = tmp % HH; tmp /= HH;
    int c = tmp % CCH; int b = tmp / CCH;
    const float* base = x1 + ((size_t)(b * CCH + c)) * LSEQ;
    float acc = 0.f;
#pragma unroll
    for (int dh = -1; dh <= 1; dh++) {
        int hh = h + dh;
        if (hh < 0 || hh >= HH) continue;
#pragma unroll
        for (int dw = -1; dw <= 1; dw++) {
            int wcol = w + dw;
            if (wcol < 0 || wcol >= WW) continue;
            acc += wdw[c * 9 + (dh + 1) * 3 + (dw + 1)] * base[hh * WW + wcol];
        }
    }
    float bn = (acc - bn_mean[c]) * rsqrtf(bn_var[c] + 1e-5f) * bn_g[c] + bn_b[c];
    x2[idx] = x1[idx] + geluf(bn);
}

// ---------------- out = x2 + transpose(mlp_out) + b2 ----------------
__global__ __launch_bounds__(256) void final_add(const float* __restrict__ x2,
                                                 const float* __restrict__ mo,
                                                 const float* __restrict__ b2,
                                                 float* __restrict__ out) {
    int idx = blockIdx.x * 256 + threadIdx.x;
    if (idx >= NTOK * CCH) return;
    int w = idx % WW; int tmp = idx / WW;
    int h = tmp % HH; tmp /= HH;
    int c = tmp % CCH; int b = tmp / CCH;
    int m = b * LSEQ + h * WW + w;
    out[idx] = x2[idx] + mo[(size_t)m * CCH + c] + b2[c];
}

extern "C" void kernel_launch(void* const* d_in, const int* in_sizes, int n_in,
                              void* d_out, int out_size, void* d_ws, size_t ws_size,
                              hipStream_t stream) {
    const float* x         = (const float*)d_in[0];
    const float* ln1_g     = (const float*)d_in[1];
    const float* ln1_b     = (const float*)d_in[2];
    const float* in_proj_w = (const float*)d_in[3];   // (768,192)
    const float* conv_w    = (const float*)d_in[4];   // (384,1,3)
    const float* conv_b    = (const float*)d_in[5];
    const float* x_proj_w  = (const float*)d_in[6];   // (44,384)
    const float* dt_proj_w = (const float*)d_in[7];   // (384,12)
    const float* dt_proj_b = (const float*)d_in[8];
    const float* A_log     = (const float*)d_in[9];   // (384,16)
    const float* Dskip     = (const float*)d_in[10];
    const float* out_proj_w= (const float*)d_in[11];  // (192,384)
    const float* dw_w      = (const float*)d_in[12];  // (192,1,3,3)
    const float* bn_g      = (const float*)d_in[13];
    const float* bn_b      = (const float*)d_in[14];
    const float* bn_mean   = (const float*)d_in[15];
    const float* bn_var    = (const float*)d_in[16];
    const float* ln2_g     = (const float*)d_in[17];
    const float* ln2_b     = (const float*)d_in[18];
    const float* mlp_w1    = (const float*)d_in[19];  // (768,192)
    const float* mlp_b1    = (const float*)d_in[20];
    const float* mlp_w2    = (const float*)d_in[21];  // (192,768)
    const float* mlp_b2    = (const float*)d_in[22];
    float* out = (float*)d_out;

    float* ws = (float*)d_ws;
    float* tokens = ws;                                   // NTOK*192 (reused for LN2 out)
    float* xz     = tokens + (size_t)NTOK * CCH;          // NTOK*768 (reused for mlp hidden)
    float* xm_act = xz     + (size_t)NTOK * 2 * DIN;      // NTOK*384
    float* xdbl   = xm_act + (size_t)NTOK * DIN;          // NTOK*44
    float* deltab = xdbl   + (size_t)NTOK * XDM;          // NTOK*384
    float* ybuf   = deltab + (size_t)NTOK * DIN;          // NTOK*384
    float* mo     = ybuf   + (size_t)NTOK * DIN;          // NTOK*192 (reused for mlp2 out)
    float* x1     = mo     + (size_t)NTOK * CCH;          // NTOK*192
    float* x2     = x1     + (size_t)NTOK * CCH;          // NTOK*192

    // 1) LN1: x (NCHW) -> tokens (NTOK, C)
    ln_kernel<<<NTOK / 4, 256, 0, stream>>>(x, ln1_g, ln1_b, tokens);
    // 2) in_proj: tokens @ in_proj_w^T -> xz (NTOK, 768)
    gemm_nt<0><<<dim3(768 / 64, NTOK / 64), 256, 0, stream>>>(tokens, CCH, in_proj_w, nullptr, xz, NTOK, 2 * DIN, CCH);
    // 3) causal conv1d + silu -> xm_act (NTOK, 384)
    conv1d_silu<<<(NTOK * DIN + 255) / 256, 256, 0, stream>>>(xz, conv_w, conv_b, xm_act);
    // 4) x_proj: xm_act @ x_proj_w^T -> xdbl (NTOK, 44)
    gemm_nt<0><<<dim3((XDM + 63) / 64, NTOK / 64), 256, 0, stream>>>(xm_act, DIN, x_proj_w, nullptr, xdbl, NTOK, XDM, DIN);
    // 5) dt_proj + softplus -> delta (NTOK, 384)
    gemm_nt<1><<<dim3(DIN / 64, NTOK / 64), 256, 0, stream>>>(xdbl, XDM, dt_proj_w, dt_proj_b, deltab, NTOK, DIN, DTR);
    // 6) selective scan + gate -> ybuf (NTOK, 384)
    scan_kernel<<<(BATCH * DIN * DST) / 256, 256, 0, stream>>>(deltab, xm_act, xdbl, xz, A_log, Dskip, ybuf);
    // 7) out_proj: ybuf @ out_proj_w^T -> mo (NTOK, 192)
    gemm_nt<0><<<dim3(CCH / 64, NTOK / 64), 256, 0, stream>>>(ybuf, DIN, out_proj_w, nullptr, mo, NTOK, CCH, DIN);
    // 8) x1 = x + transpose(mo)
    add_tr<<<(NTOK * CCH + 255) / 256, 256, 0, stream>>>(x, mo, x1);
    // 9) x2 = x1 + gelu(bn(dwconv3x3(x1)))
    dwconv_bn_gelu<<<(NTOK * CCH + 255) / 256, 256, 0, stream>>>(x1, dw_w, bn_g, bn_b, bn_mean, bn_var, x2);
    // 10) LN2: x2 -> tokens
    ln_kernel<<<NTOK / 4, 256, 0, stream>>>(x2, ln2_g, ln2_b, tokens);
    // 11) mlp1 + bias + gelu -> xz (NTOK, 768)
    gemm_nt<2><<<dim3(768 / 64, NTOK / 64), 256, 0, stream>>>(tokens, CCH, mlp_w1, mlp_b1, xz, NTOK, 4 * CCH, CCH);
    // 12) mlp2 -> mo (NTOK, 192)
    gemm_nt<0><<<dim3(CCH / 64, NTOK / 64), 256, 0, stream>>>(xz, 4 * CCH, mlp_w2, nullptr, mo, NTOK, CCH, 4 * CCH);
    // 13) out = x2 + transpose(mo) + b2
    final_add<<<(NTOK * CCH + 255) / 256, 256, 0, stream>>>(x2, mo, mlp_b2, out);
}

// Round 2
// 880.425 us; speedup vs baseline: 3.4162x; 3.4162x over previous
//
#include <hip/hip_runtime.h>
#include <hip/hip_bf16.h>
#include <math.h>

// ---- problem constants ----
#define BATCH 4
#define CCH   192
#define HH    56
#define WW    56
#define LSEQ  (HH*WW)          // 3136
#define NTOK  (BATCH*LSEQ)     // 12544
#define DST   16               // D_STATE
#define DIN   384              // D_INNER
#define DTR   12               // DT_RANK
#define XDM   (DTR + 2*DST)    // 44
#define CL    64               // scan chunk length
#define NC    (LSEQ/CL)        // 49 chunks

__device__ __forceinline__ float siluf(float x)  { return x / (1.f + __expf(-x)); }
__device__ __forceinline__ float geluf(float x)  { return 0.5f * x * (1.f + erff(x * 0.70710678118654752f)); }
__device__ __forceinline__ float softplusf(float x) { return (x > 20.f) ? x : log1pf(__expf(x)); }

// ---------------- LayerNorm over C, NCHW input -> (B*L, C) tokens ----------------
__global__ __launch_bounds__(256) void ln_kernel(const float* __restrict__ x,
                                                 const float* __restrict__ g,
                                                 const float* __restrict__ bta,
                                                 float* __restrict__ out) {
    int row  = blockIdx.x * 4 + (threadIdx.x >> 6);
    int lane = threadIdx.x & 63;
    if (row >= NTOK) return;
    int b  = row / LSEQ;
    int hw = row % LSEQ;
    const float* xp = x + (size_t)b * CCH * LSEQ + hw;
    float v[3];
    float s = 0.f, s2 = 0.f;
#pragma unroll
    for (int i = 0; i < 3; i++) {
        int c = lane + i * 64;
        float val = xp[(size_t)c * LSEQ];
        v[i] = val; s += val; s2 += val * val;
    }
#pragma unroll
    for (int m = 32; m >= 1; m >>= 1) { s += __shfl_xor(s, m); s2 += __shfl_xor(s2, m); }
    float mean = s * (1.f / CCH);
    float var  = s2 * (1.f / CCH) - mean * mean;
    float rstd = rsqrtf(var + 1e-5f);
    float* op = out + (size_t)row * CCH;
#pragma unroll
    for (int i = 0; i < 3; i++) {
        int c = lane + i * 64;
        op[c] = (v[i] - mean) * rstd * g[c] + bta[c];
    }
}

// ---------------- generic fp32 GEMM: C[M,N] = A[M,K(lda)] * W[N,K]^T ----------------
template<int EPI>
__global__ __launch_bounds__(256) void gemm_nt(const float* __restrict__ A, int lda,
                                               const float* __restrict__ Wt,
                                               const float* __restrict__ bias,
                                               float* __restrict__ Cout,
                                               int M, int N, int K) {
    __shared__ float As[16][64 + 1];
    __shared__ float Ws[16][64 + 1];
    int tid = threadIdx.x;
    int bm = blockIdx.y * 64;
    int bn = blockIdx.x * 64;
    int lr = tid >> 4;
    int lk = tid & 15;
    int tm = (tid >> 4) << 2;
    int tn = (tid & 15) << 2;
    float acc[4][4] = {};
    for (int k0 = 0; k0 < K; k0 += 16) {
#pragma unroll
        for (int p = 0; p < 4; p++) {
            int m = bm + lr + 16 * p;
            int k = k0 + lk;
            float v = 0.f;
            if (m < M && k < K) v = A[(size_t)m * lda + k];
            As[lk][lr + 16 * p] = v;
        }
#pragma unroll
        for (int p = 0; p < 4; p++) {
            int n = bn + lr + 16 * p;
            int k = k0 + lk;
            float v = 0.f;
            if (n < N && k < K) v = Wt[(size_t)n * K + k];
            Ws[lk][lr + 16 * p] = v;
        }
        __syncthreads();
#pragma unroll
        for (int kk = 0; kk < 16; kk++) {
            float a[4], w[4];
#pragma unroll
            for (int i = 0; i < 4; i++) a[i] = As[kk][tm + i];
#pragma unroll
            for (int j = 0; j < 4; j++) w[j] = Ws[kk][tn + j];
#pragma unroll
            for (int i = 0; i < 4; i++)
#pragma unroll
                for (int j = 0; j < 4; j++)
                    acc[i][j] += a[i] * w[j];
        }
        __syncthreads();
    }
#pragma unroll
    for (int i = 0; i < 4; i++) {
        int m = bm + tm + i;
        if (m >= M) continue;
#pragma unroll
        for (int j = 0; j < 4; j++) {
            int n = bn + tn + j;
            if (n >= N) continue;
            float v = acc[i][j];
            if (EPI == 1) { v += bias[n]; v = softplusf(v); }
            else if (EPI == 2) { v += bias[n]; v = geluf(v); }
            Cout[(size_t)m * N + n] = v;
        }
    }
}

// ---------------- causal depthwise conv1d (k=3) + SiLU ----------------
__global__ __launch_bounds__(256) void conv1d_silu(const float* __restrict__ xz,
                                                   const float* __restrict__ w,
                                                   const float* __restrict__ bias,
                                                   float* __restrict__ out) {
    int idx = blockIdx.x * 256 + threadIdx.x;
    if (idx >= NTOK * DIN) return;
    int m = idx / DIN, d = idx % DIN;
    int l = m % LSEQ;
    float w0 = w[d * 3 + 0], w1 = w[d * 3 + 1], w2 = w[d * 3 + 2];
    float acc = bias[d] + w2 * xz[(size_t)m * (2 * DIN) + d];
    if (l >= 1) acc += w1 * xz[(size_t)(m - 1) * (2 * DIN) + d];
    if (l >= 2) acc += w0 * xz[(size_t)(m - 2) * (2 * DIN) + d];
    out[idx] = siluf(acc);
}

// ---------------- chunked selective scan ----------------
// phase 1: per (b,chunk,d,n) compute chunk transfer (P = prod dA, Q = local scan from 0)
__global__ __launch_bounds__(256) void scan_phase1(const float* __restrict__ delta,
                                                   const float* __restrict__ xm,
                                                   const float* __restrict__ xdbl,
                                                   const float* __restrict__ A_log,
                                                   float* __restrict__ Pbuf,
                                                   float* __restrict__ Qbuf) {
    int tid = threadIdx.x;
    int d = blockIdx.y * 16 + (tid >> 4);
    int n = tid & 15;
    int b = blockIdx.z;
    int c = blockIdx.x;
    float An = -__expf(A_log[d * DST + n]);
    float P = 1.f, Q = 0.f;
    int m0 = b * LSEQ + c * CL;
    for (int i = 0; i < CL; i++) {
        int m = m0 + i;
        float dlt = delta[(size_t)m * DIN + d];
        float xv  = xm[(size_t)m * DIN + d];
        float Bv  = xdbl[(size_t)m * XDM + DTR + n];
        float dA = __expf(dlt * An);
        P *= dA;
        Q = dA * Q + (dlt * xv) * Bv;
    }
    size_t o = ((size_t)(b * NC + c) * DIN + d) * DST + n;
    Pbuf[o] = P;
    Qbuf[o] = Q;
}

// phase 2: sequential combine over chunks (49 steps, 24576 threads)
__global__ __launch_bounds__(256) void scan_phase2(const float* __restrict__ Pbuf,
                                                   const float* __restrict__ Qbuf,
                                                   float* __restrict__ Hin) {
    int t = blockIdx.x * 256 + threadIdx.x;
    if (t >= BATCH * DIN * DST) return;
    int b = t / (DIN * DST);
    int rem = t % (DIN * DST);
    float h = 0.f;
    for (int c = 0; c < NC; c++) {
        size_t o = (size_t)(b * NC + c) * (DIN * DST) + rem;
        Hin[o] = h;
        h = Pbuf[o] * h + Qbuf[o];
    }
}

// phase 3: re-scan each chunk from its true h_in, emit gated y
__global__ __launch_bounds__(256) void scan_phase3(const float* __restrict__ delta,
                                                   const float* __restrict__ xm,
                                                   const float* __restrict__ xdbl,
                                                   const float* __restrict__ xz,
                                                   const float* __restrict__ A_log,
                                                   const float* __restrict__ Dskip,
                                                   const float* __restrict__ Hin,
                                                   float* __restrict__ ybuf) {
    int tid = threadIdx.x;
    int d = blockIdx.y * 16 + (tid >> 4);
    int n = tid & 15;
    int b = blockIdx.z;
    int c = blockIdx.x;
    float An = -__expf(A_log[d * DST + n]);
    float Dv = Dskip[d];
    size_t o = ((size_t)(b * NC + c) * DIN + d) * DST + n;
    float h = Hin[o];
    int m0 = b * LSEQ + c * CL;
    for (int i = 0; i < CL; i++) {
        int m = m0 + i;
        float dlt = delta[(size_t)m * DIN + d];
        float xv  = xm[(size_t)m * DIN + d];
        float Bv  = xdbl[(size_t)m * XDM + DTR + n];
        float Cv  = xdbl[(size_t)m * XDM + DTR + DST + n];
        float dA = __expf(dlt * An);
        h = dA * h + (dlt * xv) * Bv;
        float yp = h * Cv;
        yp += __shfl_xor(yp, 1);
        yp += __shfl_xor(yp, 2);
        yp += __shfl_xor(yp, 4);
        yp += __shfl_xor(yp, 8);
        if (n == 0) {
            float zv = xz[(size_t)m * (2 * DIN) + DIN + d];
            ybuf[(size_t)m * DIN + d] = (yp + xv * Dv) * siluf(zv);
        }
    }
}

// ---------------- x1 = x + transpose(mamba_out) ----------------
__global__ __launch_bounds__(256) void add_tr(const float* __restrict__ x,
                                              const float* __restrict__ mo,
                                              float* __restrict__ x1) {
    int idx = blockIdx.x * 256 + threadIdx.x;
    if (idx >= NTOK * CCH) return;
    int w = idx % WW; int tmp = idx / WW;
    int h = tmp % HH; tmp /= HH;
    int c = tmp % CCH; int b = tmp / CCH;
    int m = b * LSEQ + h * WW + w;
    x1[idx] = x[idx] + mo[(size_t)m * CCH + c];
}

// ---------------- depthwise 3x3 conv + BN + GELU + residual ----------------
__global__ __launch_bounds__(256) void dwconv_bn_gelu(const float* __restrict__ x1,
                                                      const float* __restrict__ wdw,
                                                      const float* __restrict__ bn_g,
                                                      const float* __restrict__ bn_b,
                                                      const float* __restrict__ bn_mean,
                                                      const float* __restrict__ bn_var,
                                                      float* __restrict__ x2) {
    int idx = blockIdx.x * 256 + threadIdx.x;
    if (idx >= NTOK * CCH) return;
    int w = idx % WW; int tmp = idx / WW;
    int h = tmp % HH; tmp /= HH;
    int c = tmp % CCH; int b = tmp / CCH;
    const float* base = x1 + ((size_t)(b * CCH + c)) * LSEQ;
    float acc = 0.f;
#pragma unroll
    for (int dh = -1; dh <= 1; dh++) {
        int hh = h + dh;
        if (hh < 0 || hh >= HH) continue;
#pragma unroll
        for (int dw = -1; dw <= 1; dw++) {
            int wcol = w + dw;
            if (wcol < 0 || wcol >= WW) continue;
            acc += wdw[c * 9 + (dh + 1) * 3 + (dw + 1)] * base[hh * WW + wcol];
        }
    }
    float bn = (acc - bn_mean[c]) * rsqrtf(bn_var[c] + 1e-5f) * bn_g[c] + bn_b[c];
    x2[idx] = x1[idx] + geluf(bn);
}

// ---------------- out = x2 + transpose(mlp_out) + b2 ----------------
__global__ __launch_bounds__(256) void final_add(const float* __restrict__ x2,
                                                 const float* __restrict__ mo,
                                                 const float* __restrict__ b2,
                                                 float* __restrict__ out) {
    int idx = blockIdx.x * 256 + threadIdx.x;
    if (idx >= NTOK * CCH) return;
    int w = idx % WW; int tmp = idx / WW;
    int h = tmp % HH; tmp /= HH;
    int c = tmp % CCH; int b = tmp / CCH;
    int m = b * LSEQ + h * WW + w;
    out[idx] = x2[idx] + mo[(size_t)m * CCH + c] + b2[c];
}

extern "C" void kernel_launch(void* const* d_in, const int* in_sizes, int n_in,
                              void* d_out, int out_size, void* d_ws, size_t ws_size,
                              hipStream_t stream) {
    const float* x         = (const float*)d_in[0];
    const float* ln1_g     = (const float*)d_in[1];
    const float* ln1_b     = (const float*)d_in[2];
    const float* in_proj_w = (const float*)d_in[3];
    const float* conv_w    = (const float*)d_in[4];
    const float* conv_b    = (const float*)d_in[5];
    const float* x_proj_w  = (const float*)d_in[6];
    const float* dt_proj_w = (const float*)d_in[7];
    const float* dt_proj_b = (const float*)d_in[8];
    const float* A_log     = (const float*)d_in[9];
    const float* Dskip     = (const float*)d_in[10];
    const float* out_proj_w= (const float*)d_in[11];
    const float* dw_w      = (const float*)d_in[12];
    const float* bn_g      = (const float*)d_in[13];
    const float* bn_b      = (const float*)d_in[14];
    const float* bn_mean   = (const float*)d_in[15];
    const float* bn_var    = (const float*)d_in[16];
    const float* ln2_g     = (const float*)d_in[17];
    const float* ln2_b     = (const float*)d_in[18];
    const float* mlp_w1    = (const float*)d_in[19];
    const float* mlp_b1    = (const float*)d_in[20];
    const float* mlp_w2    = (const float*)d_in[21];
    const float* mlp_b2    = (const float*)d_in[22];
    float* out = (float*)d_out;

    float* ws = (float*)d_ws;
    float* tokens = ws;                                   // NTOK*192
    float* xz     = tokens + (size_t)NTOK * CCH;          // NTOK*768
    float* xm_act = xz     + (size_t)NTOK * 2 * DIN;      // NTOK*384
    float* xdbl   = xm_act + (size_t)NTOK * DIN;          // NTOK*44
    float* deltab = xdbl   + (size_t)NTOK * XDM;          // NTOK*384
    float* ybuf   = deltab + (size_t)NTOK * DIN;          // NTOK*384
    float* mo     = ybuf   + (size_t)NTOK * DIN;          // NTOK*192
    float* x1     = mo     + (size_t)NTOK * CCH;          // NTOK*192
    float* x2     = x1     + (size_t)NTOK * CCH;          // NTOK*192

    // scan scratch aliases regions not yet written at scan time
    // (mo/x1/x2 are only produced AFTER the scan completes)
    // each needs B*NC*DIN*DST = 1,204,224 floats < NTOK*192 = 2,408,448
    float* Pbuf = mo;
    float* Qbuf = x1;
    float* Hin  = x2;

    // 1) LN1
    ln_kernel<<<NTOK / 4, 256, 0, stream>>>(x, ln1_g, ln1_b, tokens);
    // 2) in_proj -> xz
    gemm_nt<0><<<dim3(768 / 64, NTOK / 64), 256, 0, stream>>>(tokens, CCH, in_proj_w, nullptr, xz, NTOK, 2 * DIN, CCH);
    // 3) conv1d + silu -> xm_act
    conv1d_silu<<<(NTOK * DIN + 255) / 256, 256, 0, stream>>>(xz, conv_w, conv_b, xm_act);
    // 4) x_proj -> xdbl
    gemm_nt<0><<<dim3((XDM + 63) / 64, NTOK / 64), 256, 0, stream>>>(xm_act, DIN, x_proj_w, nullptr, xdbl, NTOK, XDM, DIN);
    // 5) dt_proj + softplus -> deltab
    gemm_nt<1><<<dim3(DIN / 64, NTOK / 64), 256, 0, stream>>>(xdbl, XDM, dt_proj_w, dt_proj_b, deltab, NTOK, DIN, DTR);
    // 6) chunked selective scan -> ybuf
    scan_phase1<<<dim3(NC, DIN / 16, BATCH), 256, 0, stream>>>(deltab, xm_act, xdbl, A_log, Pbuf, Qbuf);
    scan_phase2<<<(BATCH * DIN * DST + 255) / 256, 256, 0, stream>>>(Pbuf, Qbuf, Hin);
    scan_phase3<<<dim3(NC, DIN / 16, BATCH), 256, 0, stream>>>(deltab, xm_act, xdbl, xz, A_log, Dskip, Hin, ybuf);
    // 7) out_proj -> mo   (overwrites Pbuf region — scan is done with it)
    gemm_nt<0><<<dim3(CCH / 64, NTOK / 64), 256, 0, stream>>>(ybuf, DIN, out_proj_w, nullptr, mo, NTOK, CCH, DIN);
    // 8) x1 = x + transpose(mo)
    add_tr<<<(NTOK * CCH + 255) / 256, 256, 0, stream>>>(x, mo, x1);
    // 9) x2 = x1 + gelu(bn(dwconv3x3(x1)))
    dwconv_bn_gelu<<<(NTOK * CCH + 255) / 256, 256, 0, stream>>>(x1, dw_w, bn_g, bn_b, bn_mean, bn_var, x2);
    // 10) LN2
    ln_kernel<<<NTOK / 4, 256, 0, stream>>>(x2, ln2_g, ln2_b, tokens);
    // 11) mlp1 + gelu -> xz
    gemm_nt<2><<<dim3(768 / 64, NTOK / 64), 256, 0, stream>>>(tokens, CCH, mlp_w1, mlp_b1, xz, NTOK, 4 * CCH, CCH);
    // 12) mlp2 -> mo
    gemm_nt<0><<<dim3(CCH / 64, NTOK / 64), 256, 0, stream>>>(xz, 4 * CCH, mlp_w2, nullptr, mo, NTOK, CCH, 4 * CCH);
    // 13) out = x2 + transpose(mo) + b2
    final_add<<<(NTOK * CCH + 255) / 256, 256, 0, stream>>>(x2, mo, mlp_b2, out);
}

// Round 3
// 504.529 us; speedup vs baseline: 5.9614x; 1.7450x over previous
//
#include <hip/hip_runtime.h>
#include <hip/hip_bf16.h>
#include <math.h>

// ---- problem constants ----
#define BATCH 4
#define CCH   192
#define HH    56
#define WW    56
#define LSEQ  (HH*WW)          // 3136
#define NTOK  (BATCH*LSEQ)     // 12544
#define DST   16               // D_STATE
#define DIN   384              // D_INNER
#define DTR   12               // DT_RANK
#define XDM   (DTR + 2*DST)    // 44
#define CL    64               // scan chunk length
#define NC    (LSEQ/CL)        // 49 chunks

typedef __attribute__((ext_vector_type(8))) short short8;
typedef __attribute__((ext_vector_type(4))) float floatx4;

__device__ __forceinline__ float siluf(float x)  { return x / (1.f + __expf(-x)); }
__device__ __forceinline__ float geluf(float x)  { return 0.5f * x * (1.f + erff(x * 0.70710678118654752f)); }
__device__ __forceinline__ float softplusf(float x) { return (x > 20.f) ? x : log1pf(__expf(x)); }

// ---------------- weight fp32 -> bf16 conversion (all 5 weights, one launch) ----------------
#define WSZ0 147456  // in_proj_w 768*192
#define WSZ1 16896   // x_proj_w 44*384
#define WSZ2 73728   // out_proj_w 192*384
#define WSZ3 147456  // mlp_w1 768*192
#define WSZ4 147456  // mlp_w2 192*768
__global__ __launch_bounds__(256) void cvt_weights(const float* __restrict__ w0, const float* __restrict__ w1,
                                                   const float* __restrict__ w2, const float* __restrict__ w3,
                                                   const float* __restrict__ w4,
                                                   __hip_bfloat16* __restrict__ o0, __hip_bfloat16* __restrict__ o1,
                                                   __hip_bfloat16* __restrict__ o2, __hip_bfloat16* __restrict__ o3,
                                                   __hip_bfloat16* __restrict__ o4) {
    int i = blockIdx.x * 256 + threadIdx.x;
    if (i < WSZ0) { o0[i] = __float2bfloat16(w0[i]); return; } i -= WSZ0;
    if (i < WSZ1) { o1[i] = __float2bfloat16(w1[i]); return; } i -= WSZ1;
    if (i < WSZ2) { o2[i] = __float2bfloat16(w2[i]); return; } i -= WSZ2;
    if (i < WSZ3) { o3[i] = __float2bfloat16(w3[i]); return; } i -= WSZ3;
    if (i < WSZ4) { o4[i] = __float2bfloat16(w4[i]); }
}

// ---------------- LayerNorm over C -> bf16 tokens ----------------
__global__ __launch_bounds__(256) void ln_kernel(const float* __restrict__ x,
                                                 const float* __restrict__ g,
                                                 const float* __restrict__ bta,
                                                 __hip_bfloat16* __restrict__ out) {
    int row  = blockIdx.x * 4 + (threadIdx.x >> 6);
    int lane = threadIdx.x & 63;
    if (row >= NTOK) return;
    int b  = row / LSEQ;
    int hw = row % LSEQ;
    const float* xp = x + (size_t)b * CCH * LSEQ + hw;
    float v[3];
    float s = 0.f, s2 = 0.f;
#pragma unroll
    for (int i = 0; i < 3; i++) {
        int c = lane + i * 64;
        float val = xp[(size_t)c * LSEQ];
        v[i] = val; s += val; s2 += val * val;
    }
#pragma unroll
    for (int m = 32; m >= 1; m >>= 1) { s += __shfl_xor(s, m); s2 += __shfl_xor(s2, m); }
    float mean = s * (1.f / CCH);
    float var  = s2 * (1.f / CCH) - mean * mean;
    float rstd = rsqrtf(var + 1e-5f);
    __hip_bfloat16* op = out + (size_t)row * CCH;
#pragma unroll
    for (int i = 0; i < 3; i++) {
        int c = lane + i * 64;
        op[c] = __float2bfloat16((v[i] - mean) * rstd * g[c] + bta[c]);
    }
}

// ---------------- bf16 MFMA GEMM: C[M=NTOK, N] = A[M,K] * W[N,K]^T ----------------
// 128x128 block tile, 4 waves in 2x2, each wave 64x64 (4x4 of 16x16x32 MFMA).
// M = NTOK = 98*128 exactly; K multiple of 32; N masked.
// EPI: 0 = none, 2 = +bias then GELU
template<int EPI, typename OutT>
__global__ __launch_bounds__(256) void gemm_mfma(const __hip_bfloat16* __restrict__ A,
                                                 const __hip_bfloat16* __restrict__ W,
                                                 const float* __restrict__ bias,
                                                 OutT* __restrict__ Cout,
                                                 int N, int K) {
    __shared__ __align__(16) __hip_bfloat16 As[128 * 40];
    __shared__ __align__(16) __hip_bfloat16 Bs[128 * 40];
    int tid = threadIdx.x;
    int bm = blockIdx.y * 128, bn = blockIdx.x * 128;
    int wave = tid >> 6, lane = tid & 63;
    int wm = (wave >> 1) * 64, wn = (wave & 1) * 64;
    int lm = lane & 15, quad = lane >> 4;
    floatx4 acc[4][4] = {};
    int lrow = tid >> 2;            // 0..63
    int lcol = (tid & 3) * 8;       // 0,8,16,24
    for (int k0 = 0; k0 < K; k0 += 32) {
#pragma unroll
        for (int p = 0; p < 2; p++) {
            int row = lrow + p * 64;
            *(short8*)&As[row * 40 + lcol] = *(const short8*)(A + (size_t)(bm + row) * K + k0 + lcol);
            int n = bn + row;
            short8 bv = {0,0,0,0,0,0,0,0};
            if (n < N) bv = *(const short8*)(W + (size_t)n * K + k0 + lcol);
            *(short8*)&Bs[row * 40 + lcol] = bv;
        }
        __syncthreads();
        short8 a[4], b[4];
#pragma unroll
        for (int i = 0; i < 4; i++) a[i] = *(const short8*)&As[(wm + i * 16 + lm) * 40 + quad * 8];
#pragma unroll
        for (int j = 0; j < 4; j++) b[j] = *(const short8*)&Bs[(wn + j * 16 + lm) * 40 + quad * 8];
#pragma unroll
        for (int i = 0; i < 4; i++)
#pragma unroll
            for (int j = 0; j < 4; j++)
                acc[i][j] = __builtin_amdgcn_mfma_f32_16x16x32_bf16(a[i], b[j], acc[i][j], 0, 0, 0);
        __syncthreads();
    }
#pragma unroll
    for (int j = 0; j < 4; j++) {
        int n = bn + wn + j * 16 + lm;
        if (n >= N) continue;
        float bv = (EPI != 0) ? bias[n] : 0.f;
#pragma unroll
        for (int i = 0; i < 4; i++) {
            int mrow = bm + wm + i * 16 + quad * 4;
#pragma unroll
            for (int r = 0; r < 4; r++) {
                float v = acc[i][j][r];
                if (EPI == 2) { v += bv; v = geluf(v); }
                Cout[(size_t)(mrow + r) * N + n] = (OutT)v;
            }
        }
    }
}

// ---------------- fp32 GEMM for dt_proj (K=12): C = A[M,44(:12)] * W[384,12]^T, +bias, softplus ----------------
__global__ __launch_bounds__(256) void gemm_nt_dt(const float* __restrict__ A,
                                                  const float* __restrict__ Wt,
                                                  const float* __restrict__ bias,
                                                  float* __restrict__ Cout) {
    __shared__ float As[16][64 + 1];
    __shared__ float Ws[16][64 + 1];
    const int M = NTOK, N = DIN, K = DTR;
    int tid = threadIdx.x;
    int bm = blockIdx.y * 64;
    int bn = blockIdx.x * 64;
    int lr = tid >> 4;
    int lk = tid & 15;
    int tm = (tid >> 4) << 2;
    int tn = (tid & 15) << 2;
    float acc[4][4] = {};
#pragma unroll
    for (int p = 0; p < 4; p++) {
        int m = bm + lr + 16 * p;
        As[lk][lr + 16 * p] = (lk < K) ? A[(size_t)m * XDM + lk] : 0.f;
        int n = bn + lr + 16 * p;
        Ws[lk][lr + 16 * p] = (lk < K) ? Wt[(size_t)n * K + lk] : 0.f;
    }
    __syncthreads();
#pragma unroll
    for (int kk = 0; kk < 12; kk++) {
        float a[4], w[4];
#pragma unroll
        for (int i = 0; i < 4; i++) a[i] = As[kk][tm + i];
#pragma unroll
        for (int j = 0; j < 4; j++) w[j] = Ws[kk][tn + j];
#pragma unroll
        for (int i = 0; i < 4; i++)
#pragma unroll
            for (int j = 0; j < 4; j++)
                acc[i][j] += a[i] * w[j];
    }
#pragma unroll
    for (int i = 0; i < 4; i++) {
        int m = bm + tm + i;
#pragma unroll
        for (int j = 0; j < 4; j++) {
            int n = bn + tn + j;
            Cout[(size_t)m * N + n] = softplusf(acc[i][j] + bias[n]);
        }
    }
}

// ---------------- causal depthwise conv1d (k=3) + SiLU; writes f32 + bf16 ----------------
__global__ __launch_bounds__(256) void conv1d_silu(const float* __restrict__ xz,
                                                   const float* __restrict__ w,
                                                   const float* __restrict__ bias,
                                                   float* __restrict__ out,
                                                   __hip_bfloat16* __restrict__ out_bf) {
    int idx = blockIdx.x * 256 + threadIdx.x;
    if (idx >= NTOK * DIN) return;
    int m = idx / DIN, d = idx % DIN;
    int l = m % LSEQ;
    float w0 = w[d * 3 + 0], w1 = w[d * 3 + 1], w2 = w[d * 3 + 2];
    float acc = bias[d] + w2 * xz[(size_t)m * (2 * DIN) + d];
    if (l >= 1) acc += w1 * xz[(size_t)(m - 1) * (2 * DIN) + d];
    if (l >= 2) acc += w0 * xz[(size_t)(m - 2) * (2 * DIN) + d];
    float v = siluf(acc);
    out[idx] = v;
    out_bf[idx] = __float2bfloat16(v);
}

// ---------------- chunked selective scan ----------------
__global__ __launch_bounds__(256) void scan_phase1(const float* __restrict__ delta,
                                                   const float* __restrict__ xm,
                                                   const float* __restrict__ xdbl,
                                                   const float* __restrict__ A_log,
                                                   float* __restrict__ Pbuf,
                                                   float* __restrict__ Qbuf) {
    int tid = threadIdx.x;
    int d = blockIdx.y * 16 + (tid >> 4);
    int n = tid & 15;
    int b = blockIdx.z;
    int c = blockIdx.x;
    float An = -__expf(A_log[d * DST + n]);
    float P = 1.f, Q = 0.f;
    int m0 = b * LSEQ + c * CL;
    for (int i = 0; i < CL; i++) {
        int m = m0 + i;
        float dlt = delta[(size_t)m * DIN + d];
        float xv  = xm[(size_t)m * DIN + d];
        float Bv  = xdbl[(size_t)m * XDM + DTR + n];
        float dA = __expf(dlt * An);
        P *= dA;
        Q = dA * Q + (dlt * xv) * Bv;
    }
    size_t o = ((size_t)(b * NC + c) * DIN + d) * DST + n;
    Pbuf[o] = P;
    Qbuf[o] = Q;
}

__global__ __launch_bounds__(256) void scan_phase2(const float* __restrict__ Pbuf,
                                                   const float* __restrict__ Qbuf,
                                                   float* __restrict__ Hin) {
    int t = blockIdx.x * 256 + threadIdx.x;
    if (t >= BATCH * DIN * DST) return;
    int b = t / (DIN * DST);
    int rem = t % (DIN * DST);
    float h = 0.f;
    for (int c = 0; c < NC; c++) {
        size_t o = (size_t)(b * NC + c) * (DIN * DST) + rem;
        Hin[o] = h;
        h = Pbuf[o] * h + Qbuf[o];
    }
}

__global__ __launch_bounds__(256) void scan_phase3(const float* __restrict__ delta,
                                                   const float* __restrict__ xm,
                                                   const float* __restrict__ xdbl,
                                                   const float* __restrict__ xz,
                                                   const float* __restrict__ A_log,
                                                   const float* __restrict__ Dskip,
                                                   const float* __restrict__ Hin,
                                                   __hip_bfloat16* __restrict__ ybuf) {
    int tid = threadIdx.x;
    int d = blockIdx.y * 16 + (tid >> 4);
    int n = tid & 15;
    int b = blockIdx.z;
    int c = blockIdx.x;
    float An = -__expf(A_log[d * DST + n]);
    float Dv = Dskip[d];
    size_t o = ((size_t)(b * NC + c) * DIN + d) * DST + n;
    float h = Hin[o];
    int m0 = b * LSEQ + c * CL;
    for (int i = 0; i < CL; i++) {
        int m = m0 + i;
        float dlt = delta[(size_t)m * DIN + d];
        float xv  = xm[(size_t)m * DIN + d];
        float Bv  = xdbl[(size_t)m * XDM + DTR + n];
        float Cv  = xdbl[(size_t)m * XDM + DTR + DST + n];
        float dA = __expf(dlt * An);
        h = dA * h + (dlt * xv) * Bv;
        float yp = h * Cv;
        yp += __shfl_xor(yp, 1);
        yp += __shfl_xor(yp, 2);
        yp += __shfl_xor(yp, 4);
        yp += __shfl_xor(yp, 8);
        if (n == 0) {
            float zv = xz[(size_t)m * (2 * DIN) + DIN + d];
            ybuf[(size_t)m * DIN + d] = __float2bfloat16((yp + xv * Dv) * siluf(zv));
        }
    }
}

// ---------------- x1 = x + transpose(mamba_out) ----------------
__global__ __launch_bounds__(256) void add_tr(const float* __restrict__ x,
                                              const float* __restrict__ mo,
                                              float* __restrict__ x1) {
    int idx = blockIdx.x * 256 + threadIdx.x;
    if (idx >= NTOK * CCH) return;
    int w = idx % WW; int tmp = idx / WW;
    int h = tmp % HH; tmp /= HH;
    int c = tmp % CCH; int b = tmp / CCH;
    int m = b * LSEQ + h * WW + w;
    x1[idx] = x[idx] + mo[(size_t)m * CCH + c];
}

// ---------------- depthwise 3x3 conv + BN + GELU + residual ----------------
__global__ __launch_bounds__(256) void dwconv_bn_gelu(const float* __restrict__ x1,
                                                      const float* __restrict__ wdw,
                                                      const float* __restrict__ bn_g,
                                                      const float* __restrict__ bn_b,
                                                      const float* __restrict__ bn_mean,
                                                      const float* __restrict__ bn_var,
                                                      float* __restrict__ x2) {
    int idx = blockIdx.x * 256 + threadIdx.x;
    if (idx >= NTOK * CCH) return;
    int w = idx % WW; int tmp = idx / WW;
    int h = tmp % HH; tmp /= HH;
    int c = tmp % CCH; int b = tmp / CCH;
    const float* base = x1 + ((size_t)(b * CCH + c)) * LSEQ;
    float acc = 0.f;
#pragma unroll
    for (int dh = -1; dh <= 1; dh++) {
        int hh = h + dh;
        if (hh < 0 || hh >= HH) continue;
#pragma unroll
        for (int dw = -1; dw <= 1; dw++) {
            int wcol = w + dw;
            if (wcol < 0 || wcol >= WW) continue;
            acc += wdw[c * 9 + (dh + 1) * 3 + (dw + 1)] * base[hh * WW + wcol];
        }
    }
    float bn = (acc - bn_mean[c]) * rsqrtf(bn_var[c] + 1e-5f) * bn_g[c] + bn_b[c];
    x2[idx] = x1[idx] + geluf(bn);
}

// ---------------- out = x2 + transpose(mlp_out) + b2 ----------------
__global__ __launch_bounds__(256) void final_add(const float* __restrict__ x2,
                                                 const float* __restrict__ mo,
                                                 const float* __restrict__ b2,
                                                 float* __restrict__ out) {
    int idx = blockIdx.x * 256 + threadIdx.x;
    if (idx >= NTOK * CCH) return;
    int w = idx % WW; int tmp = idx / WW;
    int h = tmp % HH; tmp /= HH;
    int c = tmp % CCH; int b = tmp / CCH;
    int m = b * LSEQ + h * WW + w;
    out[idx] = x2[idx] + mo[(size_t)m * CCH + c] + b2[c];
}

extern "C" void kernel_launch(void* const* d_in, const int* in_sizes, int n_in,
                              void* d_out, int out_size, void* d_ws, size_t ws_size,
                              hipStream_t stream) {
    const float* x         = (const float*)d_in[0];
    const float* ln1_g     = (const float*)d_in[1];
    const float* ln1_b     = (const float*)d_in[2];
    const float* in_proj_w = (const float*)d_in[3];
    const float* conv_w    = (const float*)d_in[4];
    const float* conv_b    = (const float*)d_in[5];
    const float* x_proj_w  = (const float*)d_in[6];
    const float* dt_proj_w = (const float*)d_in[7];
    const float* dt_proj_b = (const float*)d_in[8];
    const float* A_log     = (const float*)d_in[9];
    const float* Dskip     = (const float*)d_in[10];
    const float* out_proj_w= (const float*)d_in[11];
    const float* dw_w      = (const float*)d_in[12];
    const float* bn_g      = (const float*)d_in[13];
    const float* bn_b      = (const float*)d_in[14];
    const float* bn_mean   = (const float*)d_in[15];
    const float* bn_var    = (const float*)d_in[16];
    const float* ln2_g     = (const float*)d_in[17];
    const float* ln2_b     = (const float*)d_in[18];
    const float* mlp_w1    = (const float*)d_in[19];
    const float* mlp_b1    = (const float*)d_in[20];
    const float* mlp_w2    = (const float*)d_in[21];
    const float* mlp_b2    = (const float*)d_in[22];
    float* out = (float*)d_out;

    // ---- workspace layout (fp32 regions first, then bf16) ----
    float* ws = (float*)d_ws;
    float* xz     = ws;                                   // NTOK*768 f32
    float* xm_act = xz     + (size_t)NTOK * 768;          // NTOK*384 f32
    float* deltab = xm_act + (size_t)NTOK * DIN;          // NTOK*384 f32 (aliased by hidden_bf after scan)
    float* xdbl   = deltab + (size_t)NTOK * DIN;          // NTOK*44 f32
    float* mo     = xdbl   + (size_t)NTOK * XDM;          // NTOK*192 f32 (aliases Pbuf pre-out_proj)
    float* x1     = mo     + (size_t)NTOK * CCH;          // NTOK*192 f32 (aliases Qbuf)
    float* x2     = x1     + (size_t)NTOK * CCH;          // NTOK*192 f32 (aliases Hin)
    __hip_bfloat16* tokens_bf = (__hip_bfloat16*)(x2 + (size_t)NTOK * CCH);       // NTOK*192 bf16
    __hip_bfloat16* xm_bf     = tokens_bf + (size_t)NTOK * CCH;                   // NTOK*384 bf16
    __hip_bfloat16* ybuf_bf   = xm_bf + (size_t)NTOK * DIN;                       // NTOK*384 bf16
    __hip_bfloat16* wpool     = ybuf_bf + (size_t)NTOK * DIN;
    __hip_bfloat16* in_w_bf   = wpool;                    // 147456
    __hip_bfloat16* xp_w_bf   = in_w_bf + WSZ0;           // 16896
    __hip_bfloat16* op_w_bf   = xp_w_bf + WSZ1;           // 73728
    __hip_bfloat16* w1_bf     = op_w_bf + WSZ2;           // 147456
    __hip_bfloat16* w2_bf     = w1_bf + WSZ3;             // 147456
    // scan scratch aliases (mo/x1/x2 written only after the scan)
    float* Pbuf = mo;
    float* Qbuf = x1;
    float* Hin  = x2;
    // hidden (mlp1 out, NTOK*768 bf16 = NTOK*1536B) aliases deltab (NTOK*384 f32 = NTOK*1536B)
    __hip_bfloat16* hidden_bf = (__hip_bfloat16*)deltab;

    // 0) convert weights to bf16
    cvt_weights<<<(WSZ0 + WSZ1 + WSZ2 + WSZ3 + WSZ4 + 255) / 256, 256, 0, stream>>>(
        in_proj_w, x_proj_w, out_proj_w, mlp_w1, mlp_w2,
        in_w_bf, xp_w_bf, op_w_bf, w1_bf, w2_bf);
    // 1) LN1 -> tokens_bf
    ln_kernel<<<NTOK / 4, 256, 0, stream>>>(x, ln1_g, ln1_b, tokens_bf);
    // 2) in_proj (MFMA) -> xz f32
    gemm_mfma<0, float><<<dim3(768 / 128, NTOK / 128), 256, 0, stream>>>(tokens_bf, in_w_bf, nullptr, xz, 768, CCH);
    // 3) conv1d + silu -> xm_act f32 + xm_bf
    conv1d_silu<<<(NTOK * DIN + 255) / 256, 256, 0, stream>>>(xz, conv_w, conv_b, xm_act, xm_bf);
    // 4) x_proj (MFMA, N=44 masked) -> xdbl f32
    gemm_mfma<0, float><<<dim3(1, NTOK / 128), 256, 0, stream>>>(xm_bf, xp_w_bf, nullptr, xdbl, XDM, DIN);
    // 5) dt_proj (fp32, K=12) + softplus -> deltab
    gemm_nt_dt<<<dim3(DIN / 64, NTOK / 64), 256, 0, stream>>>(xdbl, dt_proj_w, dt_proj_b, deltab);
    // 6) chunked selective scan -> ybuf_bf
    scan_phase1<<<dim3(NC, DIN / 16, BATCH), 256, 0, stream>>>(deltab, xm_act, xdbl, A_log, Pbuf, Qbuf);
    scan_phase2<<<(BATCH * DIN * DST + 255) / 256, 256, 0, stream>>>(Pbuf, Qbuf, Hin);
    scan_phase3<<<dim3(NC, DIN / 16, BATCH), 256, 0, stream>>>(deltab, xm_act, xdbl, xz, A_log, Dskip, Hin, ybuf_bf);
    // 7) out_proj (MFMA) -> mo f32
    gemm_mfma<0, float><<<dim3(2, NTOK / 128), 256, 0, stream>>>(ybuf_bf, op_w_bf, nullptr, mo, CCH, DIN);
    // 8) x1 = x + transpose(mo)
    add_tr<<<(NTOK * CCH + 255) / 256, 256, 0, stream>>>(x, mo, x1);
    // 9) x2 = x1 + gelu(bn(dwconv3x3(x1)))
    dwconv_bn_gelu<<<(NTOK * CCH + 255) / 256, 256, 0, stream>>>(x1, dw_w, bn_g, bn_b, bn_mean, bn_var, x2);
    // 10) LN2 -> tokens_bf
    ln_kernel<<<NTOK / 4, 256, 0, stream>>>(x2, ln2_g, ln2_b, tokens_bf);
    // 11) mlp1 (MFMA) + bias + gelu -> hidden_bf
    gemm_mfma<2, __hip_bfloat16><<<dim3(768 / 128, NTOK / 128), 256, 0, stream>>>(tokens_bf, w1_bf, mlp_b1, hidden_bf, 768, CCH);
    // 12) mlp2 (MFMA) -> mo f32
    gemm_mfma<0, float><<<dim3(2, NTOK / 128), 256, 0, stream>>>(hidden_bf, w2_bf, nullptr, mo, CCH, 4 * CCH);
    // 13) out = x2 + transpose(mo) + b2
    final_add<<<(NTOK * CCH + 255) / 256, 256, 0, stream>>>(x2, mo, mlp_b2, out);
}

// Round 4
// 397.788 us; speedup vs baseline: 7.5611x; 1.2683x over previous
//
#include <hip/hip_runtime.h>
#include <hip/hip_bf16.h>
#include <math.h>

// ---- problem constants ----
#define BATCH 4
#define CCH   192
#define HH    56
#define WW    56
#define LSEQ  (HH*WW)          // 3136
#define NTOK  (BATCH*LSEQ)     // 12544
#define DST   16               // D_STATE
#define DIN   384              // D_INNER
#define DTR   12               // DT_RANK
#define XDM   (DTR + 2*DST)    // 44
#define CL    64               // scan chunk length
#define NC    (LSEQ/CL)        // 49 chunks

typedef __attribute__((ext_vector_type(8))) short short8;
typedef __attribute__((ext_vector_type(4))) float floatx4;

__device__ __forceinline__ float siluf(float x)  { return x / (1.f + __expf(-x)); }
__device__ __forceinline__ float geluf(float x)  { return 0.5f * x * (1.f + erff(x * 0.70710678118654752f)); }
__device__ __forceinline__ float softplusf(float x) { return (x > 20.f) ? x : log1pf(__expf(x)); }

// ---------------- weight fp32 -> bf16 conversion ----------------
#define WSZ0 147456  // in_proj_w 768*192
#define WSZ1 16896   // x_proj_w 44*384
#define WSZ2 73728   // out_proj_w 192*384
#define WSZ3 147456  // mlp_w1 768*192
#define WSZ4 147456  // mlp_w2 192*768
__global__ __launch_bounds__(256) void cvt_weights(const float* __restrict__ w0, const float* __restrict__ w1,
                                                   const float* __restrict__ w2, const float* __restrict__ w3,
                                                   const float* __restrict__ w4,
                                                   __hip_bfloat16* __restrict__ o0, __hip_bfloat16* __restrict__ o1,
                                                   __hip_bfloat16* __restrict__ o2, __hip_bfloat16* __restrict__ o3,
                                                   __hip_bfloat16* __restrict__ o4) {
    int i = blockIdx.x * 256 + threadIdx.x;
    if (i < WSZ0) { o0[i] = __float2bfloat16(w0[i]); return; } i -= WSZ0;
    if (i < WSZ1) { o1[i] = __float2bfloat16(w1[i]); return; } i -= WSZ1;
    if (i < WSZ2) { o2[i] = __float2bfloat16(w2[i]); return; } i -= WSZ2;
    if (i < WSZ3) { o3[i] = __float2bfloat16(w3[i]); return; } i -= WSZ3;
    if (i < WSZ4) { o4[i] = __float2bfloat16(w4[i]); }
}

// ---------------- LayerNorm over C -> bf16 tokens ----------------
__global__ __launch_bounds__(256) void ln_kernel(const float* __restrict__ x,
                                                 const float* __restrict__ g,
                                                 const float* __restrict__ bta,
                                                 __hip_bfloat16* __restrict__ out) {
    int row  = blockIdx.x * 4 + (threadIdx.x >> 6);
    int lane = threadIdx.x & 63;
    if (row >= NTOK) return;
    int b  = row / LSEQ;
    int hw = row % LSEQ;
    const float* xp = x + (size_t)b * CCH * LSEQ + hw;
    float v[3];
    float s = 0.f, s2 = 0.f;
#pragma unroll
    for (int i = 0; i < 3; i++) {
        int c = lane + i * 64;
        float val = xp[(size_t)c * LSEQ];
        v[i] = val; s += val; s2 += val * val;
    }
#pragma unroll
    for (int m = 32; m >= 1; m >>= 1) { s += __shfl_xor(s, m); s2 += __shfl_xor(s2, m); }
    float mean = s * (1.f / CCH);
    float var  = s2 * (1.f / CCH) - mean * mean;
    float rstd = rsqrtf(var + 1e-5f);
    __hip_bfloat16* op = out + (size_t)row * CCH;
#pragma unroll
    for (int i = 0; i < 3; i++) {
        int c = lane + i * 64;
        op[c] = __float2bfloat16((v[i] - mean) * rstd * g[c] + bta[c]);
    }
}

// ---------------- bf16 MFMA GEMM: C[M=NTOK, N] = A[M,K] * W[N,K]^T ----------------
// 128x128 block tile, 4 waves 2x2, each wave 64x64 (4x4 of 16x16x32 MFMA).
// EPI: 0 = plain store to [M,N]
//      2 = +bias, GELU, store to [M,N] (OutT may be bf16)
//      3 = +res (NCHW), transposed float4 store to NCHW   (x1 = x + mamba_out)
//      4 = +bias +res (NCHW), transposed float4 store NCHW (out = x2 + mlp2 + b2)
template<int EPI, typename OutT>
__global__ __launch_bounds__(256) void gemm_mfma(const __hip_bfloat16* __restrict__ A,
                                                 const __hip_bfloat16* __restrict__ W,
                                                 const float* __restrict__ bias,
                                                 const float* __restrict__ res,
                                                 OutT* __restrict__ Cout,
                                                 int N, int K) {
    __shared__ __align__(16) __hip_bfloat16 As[128 * 40];
    __shared__ __align__(16) __hip_bfloat16 Bs[128 * 40];
    int tid = threadIdx.x;
    int bm = blockIdx.y * 128, bn = blockIdx.x * 128;
    int wave = tid >> 6, lane = tid & 63;
    int wm = (wave >> 1) * 64, wn = (wave & 1) * 64;
    int lm = lane & 15, quad = lane >> 4;
    floatx4 acc[4][4] = {};
    int lrow = tid >> 2;            // 0..63
    int lcol = (tid & 3) * 8;       // 0,8,16,24
    for (int k0 = 0; k0 < K; k0 += 32) {
#pragma unroll
        for (int p = 0; p < 2; p++) {
            int row = lrow + p * 64;
            *(short8*)&As[row * 40 + lcol] = *(const short8*)(A + (size_t)(bm + row) * K + k0 + lcol);
            int n = bn + row;
            short8 bv = {0,0,0,0,0,0,0,0};
            if (n < N) bv = *(const short8*)(W + (size_t)n * K + k0 + lcol);
            *(short8*)&Bs[row * 40 + lcol] = bv;
        }
        __syncthreads();
        short8 a[4], b[4];
#pragma unroll
        for (int i = 0; i < 4; i++) a[i] = *(const short8*)&As[(wm + i * 16 + lm) * 40 + quad * 8];
#pragma unroll
        for (int j = 0; j < 4; j++) b[j] = *(const short8*)&Bs[(wn + j * 16 + lm) * 40 + quad * 8];
#pragma unroll
        for (int i = 0; i < 4; i++)
#pragma unroll
            for (int j = 0; j < 4; j++)
                acc[i][j] = __builtin_amdgcn_mfma_f32_16x16x32_bf16(a[i], b[j], acc[i][j], 0, 0, 0);
        __syncthreads();
    }
#pragma unroll
    for (int j = 0; j < 4; j++) {
        int n = bn + wn + j * 16 + lm;
        if (n >= N) continue;
        float bv = (EPI == 2 || EPI == 4) ? bias[n] : 0.f;
#pragma unroll
        for (int i = 0; i < 4; i++) {
            int mrow = bm + wm + i * 16 + quad * 4;   // 4 consecutive m rows
            if (EPI == 3 || EPI == 4) {
                // transposed NCHW store: m = b*LSEQ + l; 4 rows share b (l%4==0)
                int bb = mrow / LSEQ;
                int l0 = mrow % LSEQ;
                size_t oidx = ((size_t)(bb * CCH + n)) * LSEQ + l0;
                float4 xr = *(const float4*)(res + oidx);
                float4 v;
                v.x = acc[i][j][0] + bv + xr.x;
                v.y = acc[i][j][1] + bv + xr.y;
                v.z = acc[i][j][2] + bv + xr.z;
                v.w = acc[i][j][3] + bv + xr.w;
                *(float4*)((float*)Cout + oidx) = v;
            } else {
#pragma unroll
                for (int r = 0; r < 4; r++) {
                    float v = acc[i][j][r];
                    if (EPI == 2) { v += bv; v = geluf(v); }
                    Cout[(size_t)(mrow + r) * N + n] = (OutT)v;
                }
            }
        }
    }
}

// ---------------- fp32 GEMM for dt_proj (K=12) + softplus ----------------
__global__ __launch_bounds__(256) void gemm_nt_dt(const float* __restrict__ A,
                                                  const float* __restrict__ Wt,
                                                  const float* __restrict__ bias,
                                                  float* __restrict__ Cout) {
    __shared__ float As[16][64 + 1];
    __shared__ float Ws[16][64 + 1];
    const int N = DIN, K = DTR;
    int tid = threadIdx.x;
    int bm = blockIdx.y * 64;
    int bn = blockIdx.x * 64;
    int lr = tid >> 4;
    int lk = tid & 15;
    int tm = (tid >> 4) << 2;
    int tn = (tid & 15) << 2;
    float acc[4][4] = {};
#pragma unroll
    for (int p = 0; p < 4; p++) {
        int m = bm + lr + 16 * p;
        As[lk][lr + 16 * p] = (lk < K) ? A[(size_t)m * XDM + lk] : 0.f;
        int n = bn + lr + 16 * p;
        Ws[lk][lr + 16 * p] = (lk < K) ? Wt[(size_t)n * K + lk] : 0.f;
    }
    __syncthreads();
#pragma unroll
    for (int kk = 0; kk < 12; kk++) {
        float a[4], w[4];
#pragma unroll
        for (int i = 0; i < 4; i++) a[i] = As[kk][tm + i];
#pragma unroll
        for (int j = 0; j < 4; j++) w[j] = Ws[kk][tn + j];
#pragma unroll
        for (int i = 0; i < 4; i++)
#pragma unroll
            for (int j = 0; j < 4; j++)
                acc[i][j] += a[i] * w[j];
    }
#pragma unroll
    for (int i = 0; i < 4; i++) {
        int m = bm + tm + i;
#pragma unroll
        for (int j = 0; j < 4; j++) {
            int n = bn + tn + j;
            Cout[(size_t)m * N + n] = softplusf(acc[i][j] + bias[n]);
        }
    }
}

// ---------------- causal depthwise conv1d (k=3) + SiLU; writes f32 + bf16 ----------------
__global__ __launch_bounds__(256) void conv1d_silu(const float* __restrict__ xz,
                                                   const float* __restrict__ w,
                                                   const float* __restrict__ bias,
                                                   float* __restrict__ out,
                                                   __hip_bfloat16* __restrict__ out_bf) {
    int idx = blockIdx.x * 256 + threadIdx.x;
    if (idx >= NTOK * DIN) return;
    int m = idx / DIN, d = idx % DIN;
    int l = m % LSEQ;
    float w0 = w[d * 3 + 0], w1 = w[d * 3 + 1], w2 = w[d * 3 + 2];
    float acc = bias[d] + w2 * xz[(size_t)m * (2 * DIN) + d];
    if (l >= 1) acc += w1 * xz[(size_t)(m - 1) * (2 * DIN) + d];
    if (l >= 2) acc += w0 * xz[(size_t)(m - 2) * (2 * DIN) + d];
    float v = siluf(acc);
    out[idx] = v;
    out_bf[idx] = __float2bfloat16(v);
}

// ---------------- chunked selective scan, LDS-staged ----------------
// block = 256 threads = 16 d x 16 n; grid (NC, DIN/16, BATCH)
__global__ __launch_bounds__(256) void scan_phase1(const float* __restrict__ delta,
                                                   const float* __restrict__ xm,
                                                   const float* __restrict__ xdbl,
                                                   const float* __restrict__ A_log,
                                                   float* __restrict__ Pbuf,
                                                   float* __restrict__ Qbuf) {
    __shared__ float dl_s[CL][16];
    __shared__ float xm_s[CL][16];
    __shared__ float bc_s[CL][32];
    int tid = threadIdx.x;
    int b = blockIdx.z, c = blockIdx.x, d0 = blockIdx.y * 16;
    int m0 = b * LSEQ + c * CL;
    {
        int i = tid >> 2, dq = (tid & 3) * 4;
        *(float4*)&dl_s[i][dq] = *(const float4*)&delta[(size_t)(m0 + i) * DIN + d0 + dq];
        *(float4*)&xm_s[i][dq] = *(const float4*)&xm[(size_t)(m0 + i) * DIN + d0 + dq];
        int j = tid >> 3, q = (tid & 7) * 4;
        *(float4*)&bc_s[j][q]      = *(const float4*)&xdbl[(size_t)(m0 + j) * XDM + DTR + q];
        *(float4*)&bc_s[j + 32][q] = *(const float4*)&xdbl[(size_t)(m0 + j + 32) * XDM + DTR + q];
    }
    __syncthreads();
    int dloc = tid >> 4, n = tid & 15;
    float An = -__expf(A_log[(d0 + dloc) * DST + n]);
    float P = 1.f, Q = 0.f;
#pragma unroll 4
    for (int i = 0; i < CL; i++) {
        float dlt = dl_s[i][dloc];
        float xv  = xm_s[i][dloc];
        float Bv  = bc_s[i][n];
        float dA = __expf(dlt * An);
        P *= dA;
        Q = dA * Q + (dlt * xv) * Bv;
    }
    size_t o = ((size_t)(b * NC + c) * DIN + d0 + dloc) * DST + n;
    Pbuf[o] = P;
    Qbuf[o] = Q;
}

__global__ __launch_bounds__(256) void scan_phase2(const float* __restrict__ Pbuf,
                                                   const float* __restrict__ Qbuf,
                                                   float* __restrict__ Hin) {
    int t = blockIdx.x * 256 + threadIdx.x;
    if (t >= BATCH * DIN * DST) return;
    int b = t / (DIN * DST);
    int rem = t % (DIN * DST);
    float h = 0.f;
    for (int c = 0; c < NC; c++) {
        size_t o = (size_t)(b * NC + c) * (DIN * DST) + rem;
        Hin[o] = h;
        h = Pbuf[o] * h + Qbuf[o];
    }
}

__global__ __launch_bounds__(256) void scan_phase3(const float* __restrict__ delta,
                                                   const float* __restrict__ xm,
                                                   const float* __restrict__ xdbl,
                                                   const float* __restrict__ xz,
                                                   const float* __restrict__ A_log,
                                                   const float* __restrict__ Dskip,
                                                   const float* __restrict__ Hin,
                                                   __hip_bfloat16* __restrict__ ybuf) {
    __shared__ float dl_s[CL][16];
    __shared__ float xm_s[CL][16];
    __shared__ float bc_s[CL][32];
    __shared__ float z_s[CL][16];
    int tid = threadIdx.x;
    int b = blockIdx.z, c = blockIdx.x, d0 = blockIdx.y * 16;
    int m0 = b * LSEQ + c * CL;
    {
        int i = tid >> 2, dq = (tid & 3) * 4;
        *(float4*)&dl_s[i][dq] = *(const float4*)&delta[(size_t)(m0 + i) * DIN + d0 + dq];
        *(float4*)&xm_s[i][dq] = *(const float4*)&xm[(size_t)(m0 + i) * DIN + d0 + dq];
        *(float4*)&z_s[i][dq]  = *(const float4*)&xz[(size_t)(m0 + i) * (2 * DIN) + DIN + d0 + dq];
        int j = tid >> 3, q = (tid & 7) * 4;
        *(float4*)&bc_s[j][q]      = *(const float4*)&xdbl[(size_t)(m0 + j) * XDM + DTR + q];
        *(float4*)&bc_s[j + 32][q] = *(const float4*)&xdbl[(size_t)(m0 + j + 32) * XDM + DTR + q];
    }
    __syncthreads();
    int dloc = tid >> 4, n = tid & 15;
    int d = d0 + dloc;
    float An = -__expf(A_log[d * DST + n]);
    float Dv = Dskip[d];
    size_t o = ((size_t)(b * NC + c) * DIN + d) * DST + n;
    float h = Hin[o];
#pragma unroll 4
    for (int i = 0; i < CL; i++) {
        float dlt = dl_s[i][dloc];
        float xv  = xm_s[i][dloc];
        float Bv  = bc_s[i][n];
        float Cv  = bc_s[i][16 + n];
        float dA = __expf(dlt * An);
        h = dA * h + (dlt * xv) * Bv;
        float yp = h * Cv;
        yp += __shfl_xor(yp, 1);
        yp += __shfl_xor(yp, 2);
        yp += __shfl_xor(yp, 4);
        yp += __shfl_xor(yp, 8);
        if (n == 0) {
            ybuf[(size_t)(m0 + i) * DIN + d] = __float2bfloat16((yp + xv * Dv) * siluf(z_s[i][dloc]));
        }
    }
}

// ---------------- depthwise 3x3 conv + BN + GELU + residual ----------------
__global__ __launch_bounds__(256) void dwconv_bn_gelu(const float* __restrict__ x1,
                                                      const float* __restrict__ wdw,
                                                      const float* __restrict__ bn_g,
                                                      const float* __restrict__ bn_b,
                                                      const float* __restrict__ bn_mean,
                                                      const float* __restrict__ bn_var,
                                                      float* __restrict__ x2) {
    int idx = blockIdx.x * 256 + threadIdx.x;
    if (idx >= NTOK * CCH) return;
    int w = idx % WW; int tmp = idx / WW;
    int h = tmp % HH; tmp /= HH;
    int c = tmp % CCH; int b = tmp / CCH;
    const float* base = x1 + ((size_t)(b * CCH + c)) * LSEQ;
    float acc = 0.f;
#pragma unroll
    for (int dh = -1; dh <= 1; dh++) {
        int hh = h + dh;
        if (hh < 0 || hh >= HH) continue;
#pragma unroll
        for (int dw = -1; dw <= 1; dw++) {
            int wcol = w + dw;
            if (wcol < 0 || wcol >= WW) continue;
            acc += wdw[c * 9 + (dh + 1) * 3 + (dw + 1)] * base[hh * WW + wcol];
        }
    }
    float bn = (acc - bn_mean[c]) * rsqrtf(bn_var[c] + 1e-5f) * bn_g[c] + bn_b[c];
    x2[idx] = x1[idx] + geluf(bn);
}

extern "C" void kernel_launch(void* const* d_in, const int* in_sizes, int n_in,
                              void* d_out, int out_size, void* d_ws, size_t ws_size,
                              hipStream_t stream) {
    const float* x         = (const float*)d_in[0];
    const float* ln1_g     = (const float*)d_in[1];
    const float* ln1_b     = (const float*)d_in[2];
    const float* in_proj_w = (const float*)d_in[3];
    const float* conv_w    = (const float*)d_in[4];
    const float* conv_b    = (const float*)d_in[5];
    const float* x_proj_w  = (const float*)d_in[6];
    const float* dt_proj_w = (const float*)d_in[7];
    const float* dt_proj_b = (const float*)d_in[8];
    const float* A_log     = (const float*)d_in[9];
    const float* Dskip     = (const float*)d_in[10];
    const float* out_proj_w= (const float*)d_in[11];
    const float* dw_w      = (const float*)d_in[12];
    const float* bn_g      = (const float*)d_in[13];
    const float* bn_b      = (const float*)d_in[14];
    const float* bn_mean   = (const float*)d_in[15];
    const float* bn_var    = (const float*)d_in[16];
    const float* ln2_g     = (const float*)d_in[17];
    const float* ln2_b     = (const float*)d_in[18];
    const float* mlp_w1    = (const float*)d_in[19];
    const float* mlp_b1    = (const float*)d_in[20];
    const float* mlp_w2    = (const float*)d_in[21];
    const float* mlp_b2    = (const float*)d_in[22];
    float* out = (float*)d_out;

    // ---- workspace layout ----
    float* ws = (float*)d_ws;
    float* xz     = ws;                                   // NTOK*768 f32
    float* xm_act = xz     + (size_t)NTOK * 768;          // NTOK*384 f32
    float* deltab = xm_act + (size_t)NTOK * DIN;          // NTOK*384 f32 (aliased by hidden_bf later)
    float* xdbl   = deltab + (size_t)NTOK * DIN;          // NTOK*44 f32
    float* mo     = xdbl   + (size_t)NTOK * XDM;          // NTOK*192 f32 (scan Pbuf)
    float* x1     = mo     + (size_t)NTOK * CCH;          // NTOK*192 f32 (scan Qbuf, then x1 NCHW)
    float* x2     = x1     + (size_t)NTOK * CCH;          // NTOK*192 f32 (scan Hin, then x2 NCHW)
    __hip_bfloat16* tokens_bf = (__hip_bfloat16*)(x2 + (size_t)NTOK * CCH);       // NTOK*192 bf16
    __hip_bfloat16* xm_bf     = tokens_bf + (size_t)NTOK * CCH;                   // NTOK*384 bf16
    __hip_bfloat16* ybuf_bf   = xm_bf + (size_t)NTOK * DIN;                       // NTOK*384 bf16
    __hip_bfloat16* wpool     = ybuf_bf + (size_t)NTOK * DIN;
    __hip_bfloat16* in_w_bf   = wpool;
    __hip_bfloat16* xp_w_bf   = in_w_bf + WSZ0;
    __hip_bfloat16* op_w_bf   = xp_w_bf + WSZ1;
    __hip_bfloat16* w1_bf     = op_w_bf + WSZ2;
    __hip_bfloat16* w2_bf     = w1_bf + WSZ3;
    // scan scratch aliases (x1/x2/mo written only after scan done)
    float* Pbuf = mo;
    float* Qbuf = x1;
    float* Hin  = x2;
    __hip_bfloat16* hidden_bf = (__hip_bfloat16*)deltab;  // mlp1 out aliases deltab

    // 0) weights -> bf16
    cvt_weights<<<(WSZ0 + WSZ1 + WSZ2 + WSZ3 + WSZ4 + 255) / 256, 256, 0, stream>>>(
        in_proj_w, x_proj_w, out_proj_w, mlp_w1, mlp_w2,
        in_w_bf, xp_w_bf, op_w_bf, w1_bf, w2_bf);
    // 1) LN1 -> tokens_bf
    ln_kernel<<<NTOK / 4, 256, 0, stream>>>(x, ln1_g, ln1_b, tokens_bf);
    // 2) in_proj (MFMA) -> xz f32
    gemm_mfma<0, float><<<dim3(768 / 128, NTOK / 128), 256, 0, stream>>>(tokens_bf, in_w_bf, nullptr, nullptr, xz, 768, CCH);
    // 3) conv1d + silu -> xm_act f32 + xm_bf
    conv1d_silu<<<(NTOK * DIN + 255) / 256, 256, 0, stream>>>(xz, conv_w, conv_b, xm_act, xm_bf);
    // 4) x_proj (MFMA, N=44) -> xdbl
    gemm_mfma<0, float><<<dim3(1, NTOK / 128), 256, 0, stream>>>(xm_bf, xp_w_bf, nullptr, nullptr, xdbl, XDM, DIN);
    // 5) dt_proj + softplus -> deltab
    gemm_nt_dt<<<dim3(DIN / 64, NTOK / 64), 256, 0, stream>>>(xdbl, dt_proj_w, dt_proj_b, deltab);
    // 6) chunked selective scan -> ybuf_bf
    scan_phase1<<<dim3(NC, DIN / 16, BATCH), 256, 0, stream>>>(deltab, xm_act, xdbl, A_log, Pbuf, Qbuf);
    scan_phase2<<<(BATCH * DIN * DST + 255) / 256, 256, 0, stream>>>(Pbuf, Qbuf, Hin);
    scan_phase3<<<dim3(NC, DIN / 16, BATCH), 256, 0, stream>>>(deltab, xm_act, xdbl, xz, A_log, Dskip, Hin, ybuf_bf);
    // 7) out_proj (MFMA) fused residual-add + NCHW transpose store -> x1
    gemm_mfma<3, float><<<dim3(2, NTOK / 128), 256, 0, stream>>>(ybuf_bf, op_w_bf, nullptr, x, x1, CCH, DIN);
    // 8) x2 = x1 + gelu(bn(dwconv3x3(x1)))
    dwconv_bn_gelu<<<(NTOK * CCH + 255) / 256, 256, 0, stream>>>(x1, dw_w, bn_g, bn_b, bn_mean, bn_var, x2);
    // 9) LN2 -> tokens_bf
    ln_kernel<<<NTOK / 4, 256, 0, stream>>>(x2, ln2_g, ln2_b, tokens_bf);
    // 10) mlp1 (MFMA) + bias + gelu -> hidden_bf
    gemm_mfma<2, __hip_bfloat16><<<dim3(768 / 128, NTOK / 128), 256, 0, stream>>>(tokens_bf, w1_bf, mlp_b1, nullptr, hidden_bf, 768, CCH);
    // 11) mlp2 (MFMA) fused +b2 +x2 residual, NCHW store -> out
    gemm_mfma<4, float><<<dim3(2, NTOK / 128), 256, 0, stream>>>(hidden_bf, w2_bf, mlp_b2, x2, out, CCH, 4 * CCH);
}

// Round 5
// 356.221 us; speedup vs baseline: 8.4434x; 1.1167x over previous
//
#include <hip/hip_runtime.h>
#include <hip/hip_bf16.h>
#include <math.h>

// ---- problem constants ----
#define BATCH 4
#define CCH   192
#define HH    56
#define WW    56
#define LSEQ  (HH*WW)          // 3136
#define NTOK  (BATCH*LSEQ)     // 12544
#define DST   16               // D_STATE
#define DIN   384              // D_INNER
#define DTR   12               // DT_RANK
#define XDM   (DTR + 2*DST)    // 44
#define CL    32               // scan chunk length
#define NC    (LSEQ/CL)        // 98 chunks

typedef __attribute__((ext_vector_type(8))) short short8;
typedef __attribute__((ext_vector_type(4))) float floatx4;

__device__ __forceinline__ float siluf(float x)  { return x / (1.f + __expf(-x)); }
__device__ __forceinline__ float geluf(float x)  { return 0.5f * x * (1.f + erff(x * 0.70710678118654752f)); }
__device__ __forceinline__ float softplusf(float x) { return (x > 20.f) ? x : log1pf(__expf(x)); }

// ---------------- weight fp32 -> bf16 conversion ----------------
#define WSZ0 147456  // in_proj_w 768*192
#define WSZ1 16896   // x_proj_w 44*384
#define WSZ2 73728   // out_proj_w 192*384
#define WSZ3 147456  // mlp_w1 768*192
#define WSZ4 147456  // mlp_w2 192*768
__global__ __launch_bounds__(256) void cvt_weights(const float* __restrict__ w0, const float* __restrict__ w1,
                                                   const float* __restrict__ w2, const float* __restrict__ w3,
                                                   const float* __restrict__ w4,
                                                   __hip_bfloat16* __restrict__ o0, __hip_bfloat16* __restrict__ o1,
                                                   __hip_bfloat16* __restrict__ o2, __hip_bfloat16* __restrict__ o3,
                                                   __hip_bfloat16* __restrict__ o4) {
    int i = blockIdx.x * 256 + threadIdx.x;
    if (i < WSZ0) { o0[i] = __float2bfloat16(w0[i]); return; } i -= WSZ0;
    if (i < WSZ1) { o1[i] = __float2bfloat16(w1[i]); return; } i -= WSZ1;
    if (i < WSZ2) { o2[i] = __float2bfloat16(w2[i]); return; } i -= WSZ2;
    if (i < WSZ3) { o3[i] = __float2bfloat16(w3[i]); return; } i -= WSZ3;
    if (i < WSZ4) { o4[i] = __float2bfloat16(w4[i]); }
}

// ---------------- LayerNorm over C -> bf16 tokens ----------------
__global__ __launch_bounds__(256) void ln_kernel(const float* __restrict__ x,
                                                 const float* __restrict__ g,
                                                 const float* __restrict__ bta,
                                                 __hip_bfloat16* __restrict__ out) {
    int row  = blockIdx.x * 4 + (threadIdx.x >> 6);
    int lane = threadIdx.x & 63;
    if (row >= NTOK) return;
    int b  = row / LSEQ;
    int hw = row % LSEQ;
    const float* xp = x + (size_t)b * CCH * LSEQ + hw;
    float v[3];
    float s = 0.f, s2 = 0.f;
#pragma unroll
    for (int i = 0; i < 3; i++) {
        int c = lane + i * 64;
        float val = xp[(size_t)c * LSEQ];
        v[i] = val; s += val; s2 += val * val;
    }
#pragma unroll
    for (int m = 32; m >= 1; m >>= 1) { s += __shfl_xor(s, m); s2 += __shfl_xor(s2, m); }
    float mean = s * (1.f / CCH);
    float var  = s2 * (1.f / CCH) - mean * mean;
    float rstd = rsqrtf(var + 1e-5f);
    __hip_bfloat16* op = out + (size_t)row * CCH;
#pragma unroll
    for (int i = 0; i < 3; i++) {
        int c = lane + i * 64;
        op[c] = __float2bfloat16((v[i] - mean) * rstd * g[c] + bta[c]);
    }
}

// ---------------- bf16 MFMA GEMM: C[M=NTOK, N] = A[M,K] * W[N,K]^T ----------------
// EPI: 0 = plain store, 2 = +bias+GELU, 3 = +res NCHW transposed store, 4 = +bias+res NCHW
template<int EPI, typename OutT>
__global__ __launch_bounds__(256) void gemm_mfma(const __hip_bfloat16* __restrict__ A,
                                                 const __hip_bfloat16* __restrict__ W,
                                                 const float* __restrict__ bias,
                                                 const float* __restrict__ res,
                                                 OutT* __restrict__ Cout,
                                                 int N, int K) {
    __shared__ __align__(16) __hip_bfloat16 As[128 * 40];
    __shared__ __align__(16) __hip_bfloat16 Bs[128 * 40];
    int tid = threadIdx.x;
    int bm = blockIdx.y * 128, bn = blockIdx.x * 128;
    int wave = tid >> 6, lane = tid & 63;
    int wm = (wave >> 1) * 64, wn = (wave & 1) * 64;
    int lm = lane & 15, quad = lane >> 4;
    floatx4 acc[4][4] = {};
    int lrow = tid >> 2;
    int lcol = (tid & 3) * 8;
    for (int k0 = 0; k0 < K; k0 += 32) {
#pragma unroll
        for (int p = 0; p < 2; p++) {
            int row = lrow + p * 64;
            *(short8*)&As[row * 40 + lcol] = *(const short8*)(A + (size_t)(bm + row) * K + k0 + lcol);
            int n = bn + row;
            short8 bv = {0,0,0,0,0,0,0,0};
            if (n < N) bv = *(const short8*)(W + (size_t)n * K + k0 + lcol);
            *(short8*)&Bs[row * 40 + lcol] = bv;
        }
        __syncthreads();
        short8 a[4], b[4];
#pragma unroll
        for (int i = 0; i < 4; i++) a[i] = *(const short8*)&As[(wm + i * 16 + lm) * 40 + quad * 8];
#pragma unroll
        for (int j = 0; j < 4; j++) b[j] = *(const short8*)&Bs[(wn + j * 16 + lm) * 40 + quad * 8];
#pragma unroll
        for (int i = 0; i < 4; i++)
#pragma unroll
            for (int j = 0; j < 4; j++)
                acc[i][j] = __builtin_amdgcn_mfma_f32_16x16x32_bf16(a[i], b[j], acc[i][j], 0, 0, 0);
        __syncthreads();
    }
#pragma unroll
    for (int j = 0; j < 4; j++) {
        int n = bn + wn + j * 16 + lm;
        if (n >= N) continue;
        float bv = (EPI == 2 || EPI == 4) ? bias[n] : 0.f;
#pragma unroll
        for (int i = 0; i < 4; i++) {
            int mrow = bm + wm + i * 16 + quad * 4;
            if (EPI == 3 || EPI == 4) {
                int bb = mrow / LSEQ;
                int l0 = mrow % LSEQ;
                size_t oidx = ((size_t)(bb * CCH + n)) * LSEQ + l0;
                float4 xr = *(const float4*)(res + oidx);
                float4 v;
                v.x = acc[i][j][0] + bv + xr.x;
                v.y = acc[i][j][1] + bv + xr.y;
                v.z = acc[i][j][2] + bv + xr.z;
                v.w = acc[i][j][3] + bv + xr.w;
                *(float4*)((float*)Cout + oidx) = v;
            } else {
#pragma unroll
                for (int r = 0; r < 4; r++) {
                    float v = acc[i][j][r];
                    if (EPI == 2) { v += bv; v = geluf(v); }
                    Cout[(size_t)(mrow + r) * N + n] = (OutT)v;
                }
            }
        }
    }
}

// ---------------- fp32 GEMM for dt_proj (K=12) + softplus ----------------
__global__ __launch_bounds__(256) void gemm_nt_dt(const float* __restrict__ A,
                                                  const float* __restrict__ Wt,
                                                  const float* __restrict__ bias,
                                                  float* __restrict__ Cout) {
    __shared__ float As[16][64 + 1];
    __shared__ float Ws[16][64 + 1];
    const int N = DIN, K = DTR;
    int tid = threadIdx.x;
    int bm = blockIdx.y * 64;
    int bn = blockIdx.x * 64;
    int lr = tid >> 4;
    int lk = tid & 15;
    int tm = (tid >> 4) << 2;
    int tn = (tid & 15) << 2;
    float acc[4][4] = {};
#pragma unroll
    for (int p = 0; p < 4; p++) {
        int m = bm + lr + 16 * p;
        As[lk][lr + 16 * p] = (lk < K) ? A[(size_t)m * XDM + lk] : 0.f;
        int n = bn + lr + 16 * p;
        Ws[lk][lr + 16 * p] = (lk < K) ? Wt[(size_t)n * K + lk] : 0.f;
    }
    __syncthreads();
#pragma unroll
    for (int kk = 0; kk < 12; kk++) {
        float a[4], w[4];
#pragma unroll
        for (int i = 0; i < 4; i++) a[i] = As[kk][tm + i];
#pragma unroll
        for (int j = 0; j < 4; j++) w[j] = Ws[kk][tn + j];
#pragma unroll
        for (int i = 0; i < 4; i++)
#pragma unroll
            for (int j = 0; j < 4; j++)
                acc[i][j] += a[i] * w[j];
    }
#pragma unroll
    for (int i = 0; i < 4; i++) {
        int m = bm + tm + i;
#pragma unroll
        for (int j = 0; j < 4; j++) {
            int n = bn + tn + j;
            Cout[(size_t)m * N + n] = softplusf(acc[i][j] + bias[n]);
        }
    }
}

// ---------------- causal depthwise conv1d (k=3) + SiLU; writes f32 + bf16 ----------------
__global__ __launch_bounds__(256) void conv1d_silu(const float* __restrict__ xz,
                                                   const float* __restrict__ w,
                                                   const float* __restrict__ bias,
                                                   float* __restrict__ out,
                                                   __hip_bfloat16* __restrict__ out_bf) {
    int idx = blockIdx.x * 256 + threadIdx.x;
    if (idx >= NTOK * DIN) return;
    int m = idx / DIN, d = idx % DIN;
    int l = m % LSEQ;
    float w0 = w[d * 3 + 0], w1 = w[d * 3 + 1], w2 = w[d * 3 + 2];
    float acc = bias[d] + w2 * xz[(size_t)m * (2 * DIN) + d];
    if (l >= 1) acc += w1 * xz[(size_t)(m - 1) * (2 * DIN) + d];
    if (l >= 2) acc += w0 * xz[(size_t)(m - 2) * (2 * DIN) + d];
    float v = siluf(acc);
    out[idx] = v;
    out_bf[idx] = __float2bfloat16(v);
}

// ---------------- chunked selective scan, thread-per-d ----------------
// block = 128 threads = 128 d's; grid (NC, DIN/128, BATCH)
// phase 1: P_n = exp(A_n * sum(delta)), Q_n = local scan from 0
__global__ __launch_bounds__(128) void scan_phase1(const float* __restrict__ delta,
                                                   const float* __restrict__ xm,
                                                   const float* __restrict__ xdbl,
                                                   const float* __restrict__ A_log,
                                                   float* __restrict__ Pbuf,
                                                   float* __restrict__ Qbuf) {
    __shared__ float bc_s[CL][32];
    int tid = threadIdx.x;
    int b = blockIdx.z, c = blockIdx.x, d0 = blockIdx.y * 128;
    int m0 = b * LSEQ + c * CL;
#pragma unroll
    for (int k = 0; k < 2; k++) {
        int idx = tid + k * 128;           // 0..255
        int i = idx >> 3, q = (idx & 7) * 4;
        *(float4*)&bc_s[i][q] = *(const float4*)&xdbl[(size_t)(m0 + i) * XDM + DTR + q];
    }
    __syncthreads();
    int d = d0 + tid;
    float An[16];
#pragma unroll
    for (int n4 = 0; n4 < 4; n4++) {
        float4 a = *(const float4*)&A_log[d * DST + n4 * 4];
        An[n4 * 4 + 0] = -__expf(a.x);
        An[n4 * 4 + 1] = -__expf(a.y);
        An[n4 * 4 + 2] = -__expf(a.z);
        An[n4 * 4 + 3] = -__expf(a.w);
    }
    float Q[16];
#pragma unroll
    for (int n = 0; n < 16; n++) Q[n] = 0.f;
    float s = 0.f;
    const float* dp = delta + (size_t)m0 * DIN + d;
    const float* xp = xm    + (size_t)m0 * DIN + d;
#pragma unroll 4
    for (int i = 0; i < CL; i++) {
        float dlt = dp[(size_t)i * DIN];
        float xv  = xp[(size_t)i * DIN];
        s += dlt;
        float t = dlt * xv;
        float Bv[16];
#pragma unroll
        for (int n = 0; n < 16; n++) Bv[n] = bc_s[i][n];
#pragma unroll
        for (int n = 0; n < 16; n++) {
            float dA = __expf(dlt * An[n]);
            Q[n] = dA * Q[n] + t * Bv[n];
        }
    }
    size_t o = ((size_t)(b * NC + c) * DIN + d) * DST;
#pragma unroll
    for (int n4 = 0; n4 < 4; n4++) {
        float4 Pv, Qv;
        Pv.x = __expf(An[n4 * 4 + 0] * s);
        Pv.y = __expf(An[n4 * 4 + 1] * s);
        Pv.z = __expf(An[n4 * 4 + 2] * s);
        Pv.w = __expf(An[n4 * 4 + 3] * s);
        Qv.x = Q[n4 * 4 + 0]; Qv.y = Q[n4 * 4 + 1];
        Qv.z = Q[n4 * 4 + 2]; Qv.w = Q[n4 * 4 + 3];
        *(float4*)&Pbuf[o + n4 * 4] = Pv;
        *(float4*)&Qbuf[o + n4 * 4] = Qv;
    }
}

// phase 2: sequential combine over chunks (NC steps), loads independent of fma chain
__global__ __launch_bounds__(256) void scan_phase2(const float* __restrict__ Pbuf,
                                                   const float* __restrict__ Qbuf,
                                                   float* __restrict__ Hin) {
    int t = blockIdx.x * 256 + threadIdx.x;
    if (t >= BATCH * DIN * DST) return;
    int b = t / (DIN * DST);
    int rem = t % (DIN * DST);
    float h = 0.f;
#pragma unroll 7
    for (int c = 0; c < NC; c++) {
        size_t o = (size_t)(b * NC + c) * (DIN * DST) + rem;
        Hin[o] = h;
        h = Pbuf[o] * h + Qbuf[o];
    }
}

// phase 3: re-scan from true h_in, y = sum_n h_n*C_n in-register, gate+store
__global__ __launch_bounds__(128) void scan_phase3(const float* __restrict__ delta,
                                                   const float* __restrict__ xm,
                                                   const float* __restrict__ xdbl,
                                                   const float* __restrict__ xz,
                                                   const float* __restrict__ A_log,
                                                   const float* __restrict__ Dskip,
                                                   const float* __restrict__ Hin,
                                                   __hip_bfloat16* __restrict__ ybuf) {
    __shared__ float bc_s[CL][32];
    int tid = threadIdx.x;
    int b = blockIdx.z, c = blockIdx.x, d0 = blockIdx.y * 128;
    int m0 = b * LSEQ + c * CL;
#pragma unroll
    for (int k = 0; k < 2; k++) {
        int idx = tid + k * 128;
        int i = idx >> 3, q = (idx & 7) * 4;
        *(float4*)&bc_s[i][q] = *(const float4*)&xdbl[(size_t)(m0 + i) * XDM + DTR + q];
    }
    __syncthreads();
    int d = d0 + tid;
    float An[16];
#pragma unroll
    for (int n4 = 0; n4 < 4; n4++) {
        float4 a = *(const float4*)&A_log[d * DST + n4 * 4];
        An[n4 * 4 + 0] = -__expf(a.x);
        An[n4 * 4 + 1] = -__expf(a.y);
        An[n4 * 4 + 2] = -__expf(a.z);
        An[n4 * 4 + 3] = -__expf(a.w);
    }
    float h[16];
    size_t o = ((size_t)(b * NC + c) * DIN + d) * DST;
#pragma unroll
    for (int n4 = 0; n4 < 4; n4++) {
        float4 hv = *(const float4*)&Hin[o + n4 * 4];
        h[n4 * 4 + 0] = hv.x; h[n4 * 4 + 1] = hv.y;
        h[n4 * 4 + 2] = hv.z; h[n4 * 4 + 3] = hv.w;
    }
    float Dv = Dskip[d];
    const float* dp = delta + (size_t)m0 * DIN + d;
    const float* xp = xm    + (size_t)m0 * DIN + d;
    const float* zp = xz    + (size_t)m0 * (2 * DIN) + DIN + d;
    __hip_bfloat16* yp_out = ybuf + (size_t)m0 * DIN + d;
#pragma unroll 2
    for (int i = 0; i < CL; i++) {
        float dlt = dp[(size_t)i * DIN];
        float xv  = xp[(size_t)i * DIN];
        float zv  = zp[(size_t)i * (2 * DIN)];
        float t = dlt * xv;
        float Bv[16], Cv[16];
#pragma unroll
        for (int n = 0; n < 16; n++) Bv[n] = bc_s[i][n];
#pragma unroll
        for (int n = 0; n < 16; n++) Cv[n] = bc_s[i][16 + n];
        float y = 0.f;
#pragma unroll
        for (int n = 0; n < 16; n++) {
            float dA = __expf(dlt * An[n]);
            h[n] = dA * h[n] + t * Bv[n];
            y += h[n] * Cv[n];
        }
        yp_out[(size_t)i * DIN] = __float2bfloat16((y + xv * Dv) * siluf(zv));
    }
}

// ---------------- depthwise 3x3 conv + BN + GELU + residual ----------------
__global__ __launch_bounds__(256) void dwconv_bn_gelu(const float* __restrict__ x1,
                                                      const float* __restrict__ wdw,
                                                      const float* __restrict__ bn_g,
                                                      const float* __restrict__ bn_b,
                                                      const float* __restrict__ bn_mean,
                                                      const float* __restrict__ bn_var,
                                                      float* __restrict__ x2) {
    int idx = blockIdx.x * 256 + threadIdx.x;
    if (idx >= NTOK * CCH) return;
    int w = idx % WW; int tmp = idx / WW;
    int h = tmp % HH; tmp /= HH;
    int c = tmp % CCH; int b = tmp / CCH;
    const float* base = x1 + ((size_t)(b * CCH + c)) * LSEQ;
    float acc = 0.f;
#pragma unroll
    for (int dh = -1; dh <= 1; dh++) {
        int hh = h + dh;
        if (hh < 0 || hh >= HH) continue;
#pragma unroll
        for (int dw = -1; dw <= 1; dw++) {
            int wcol = w + dw;
            if (wcol < 0 || wcol >= WW) continue;
            acc += wdw[c * 9 + (dh + 1) * 3 + (dw + 1)] * base[hh * WW + wcol];
        }
    }
    float bn = (acc - bn_mean[c]) * rsqrtf(bn_var[c] + 1e-5f) * bn_g[c] + bn_b[c];
    x2[idx] = x1[idx] + geluf(bn);
}

extern "C" void kernel_launch(void* const* d_in, const int* in_sizes, int n_in,
                              void* d_out, int out_size, void* d_ws, size_t ws_size,
                              hipStream_t stream) {
    const float* x         = (const float*)d_in[0];
    const float* ln1_g     = (const float*)d_in[1];
    const float* ln1_b     = (const float*)d_in[2];
    const float* in_proj_w = (const float*)d_in[3];
    const float* conv_w    = (const float*)d_in[4];
    const float* conv_b    = (const float*)d_in[5];
    const float* x_proj_w  = (const float*)d_in[6];
    const float* dt_proj_w = (const float*)d_in[7];
    const float* dt_proj_b = (const float*)d_in[8];
    const float* A_log     = (const float*)d_in[9];
    const float* Dskip     = (const float*)d_in[10];
    const float* out_proj_w= (const float*)d_in[11];
    const float* dw_w      = (const float*)d_in[12];
    const float* bn_g      = (const float*)d_in[13];
    const float* bn_b      = (const float*)d_in[14];
    const float* bn_mean   = (const float*)d_in[15];
    const float* bn_var    = (const float*)d_in[16];
    const float* ln2_g     = (const float*)d_in[17];
    const float* ln2_b     = (const float*)d_in[18];
    const float* mlp_w1    = (const float*)d_in[19];
    const float* mlp_b1    = (const float*)d_in[20];
    const float* mlp_w2    = (const float*)d_in[21];
    const float* mlp_b2    = (const float*)d_in[22];
    float* out = (float*)d_out;

    // ---- workspace layout ----
    float* ws = (float*)d_ws;
    float* xz     = ws;                                   // NTOK*768 f32
    float* xm_act = xz     + (size_t)NTOK * 768;          // NTOK*384 f32
    float* deltab = xm_act + (size_t)NTOK * DIN;          // NTOK*384 f32 (aliased by hidden_bf later)
    float* xdbl   = deltab + (size_t)NTOK * DIN;          // NTOK*44 f32
    float* mo     = xdbl   + (size_t)NTOK * XDM;          // NTOK*192 f32 (scan Pbuf: B*NC*DIN*DST = NTOK*192 exactly)
    float* x1     = mo     + (size_t)NTOK * CCH;          // NTOK*192 f32 (scan Qbuf, then x1 NCHW)
    float* x2     = x1     + (size_t)NTOK * CCH;          // NTOK*192 f32 (scan Hin, then x2 NCHW)
    __hip_bfloat16* tokens_bf = (__hip_bfloat16*)(x2 + (size_t)NTOK * CCH);       // NTOK*192 bf16
    __hip_bfloat16* xm_bf     = tokens_bf + (size_t)NTOK * CCH;                   // NTOK*384 bf16
    __hip_bfloat16* ybuf_bf   = xm_bf + (size_t)NTOK * DIN;                       // NTOK*384 bf16
    __hip_bfloat16* wpool     = ybuf_bf + (size_t)NTOK * DIN;
    __hip_bfloat16* in_w_bf   = wpool;
    __hip_bfloat16* xp_w_bf   = in_w_bf + WSZ0;
    __hip_bfloat16* op_w_bf   = xp_w_bf + WSZ1;
    __hip_bfloat16* w1_bf     = op_w_bf + WSZ2;
    __hip_bfloat16* w2_bf     = w1_bf + WSZ3;
    float* Pbuf = mo;
    float* Qbuf = x1;
    float* Hin  = x2;
    __hip_bfloat16* hidden_bf = (__hip_bfloat16*)deltab;  // mlp1 out aliases deltab

    // 0) weights -> bf16
    cvt_weights<<<(WSZ0 + WSZ1 + WSZ2 + WSZ3 + WSZ4 + 255) / 256, 256, 0, stream>>>(
        in_proj_w, x_proj_w, out_proj_w, mlp_w1, mlp_w2,
        in_w_bf, xp_w_bf, op_w_bf, w1_bf, w2_bf);
    // 1) LN1 -> tokens_bf
    ln_kernel<<<NTOK / 4, 256, 0, stream>>>(x, ln1_g, ln1_b, tokens_bf);
    // 2) in_proj (MFMA) -> xz f32
    gemm_mfma<0, float><<<dim3(768 / 128, NTOK / 128), 256, 0, stream>>>(tokens_bf, in_w_bf, nullptr, nullptr, xz, 768, CCH);
    // 3) conv1d + silu -> xm_act f32 + xm_bf
    conv1d_silu<<<(NTOK * DIN + 255) / 256, 256, 0, stream>>>(xz, conv_w, conv_b, xm_act, xm_bf);
    // 4) x_proj (MFMA, N=44) -> xdbl
    gemm_mfma<0, float><<<dim3(1, NTOK / 128), 256, 0, stream>>>(xm_bf, xp_w_bf, nullptr, nullptr, xdbl, XDM, DIN);
    // 5) dt_proj + softplus -> deltab
    gemm_nt_dt<<<dim3(DIN / 64, NTOK / 64), 256, 0, stream>>>(xdbl, dt_proj_w, dt_proj_b, deltab);
    // 6) chunked selective scan -> ybuf_bf
    scan_phase1<<<dim3(NC, DIN / 128, BATCH), 128, 0, stream>>>(deltab, xm_act, xdbl, A_log, Pbuf, Qbuf);
    scan_phase2<<<(BATCH * DIN * DST + 255) / 256, 256, 0, stream>>>(Pbuf, Qbuf, Hin);
    scan_phase3<<<dim3(NC, DIN / 128, BATCH), 128, 0, stream>>>(deltab, xm_act, xdbl, xz, A_log, Dskip, Hin, ybuf_bf);
    // 7) out_proj (MFMA) fused residual-add + NCHW transpose store -> x1
    gemm_mfma<3, float><<<dim3(2, NTOK / 128), 256, 0, stream>>>(ybuf_bf, op_w_bf, nullptr, x, x1, CCH, DIN);
    // 8) x2 = x1 + gelu(bn(dwconv3x3(x1)))
    dwconv_bn_gelu<<<(NTOK * CCH + 255) / 256, 256, 0, stream>>>(x1, dw_w, bn_g, bn_b, bn_mean, bn_var, x2);
    // 9) LN2 -> tokens_bf
    ln_kernel<<<NTOK / 4, 256, 0, stream>>>(x2, ln2_g, ln2_b, tokens_bf);
    // 10) mlp1 (MFMA) + bias + gelu -> hidden_bf
    gemm_mfma<2, __hip_bfloat16><<<dim3(768 / 128, NTOK / 128), 256, 0, stream>>>(tokens_bf, w1_bf, mlp_b1, nullptr, hidden_bf, 768, CCH);
    // 11) mlp2 (MFMA) fused +b2 +x2 residual, NCHW store -> out
    gemm_mfma<4, float><<<dim3(2, NTOK / 128), 256, 0, stream>>>(hidden_bf, w2_bf, mlp_b2, x2, out, CCH, 4 * CCH);
}

// Round 6
// 321.567 us; speedup vs baseline: 9.3533x; 1.1078x over previous
//
#include <hip/hip_runtime.h>
#include <hip/hip_bf16.h>
#include <math.h>

// ---- problem constants ----
#define BATCH 4
#define CCH   192
#define HH    56
#define WW    56
#define LSEQ  (HH*WW)          // 3136
#define NTOK  (BATCH*LSEQ)     // 12544
#define DST   16               // D_STATE
#define DIN   384              // D_INNER
#define DTR   12               // DT_RANK
#define XDM   (DTR + 2*DST)    // 44
#define CL    32               // scan chunk length
#define NC    (LSEQ/CL)        // 98 chunks

typedef __attribute__((ext_vector_type(8))) short short8;
typedef __attribute__((ext_vector_type(4))) short short4v;
typedef __attribute__((ext_vector_type(4))) float floatx4;

__device__ __forceinline__ float siluf(float x)  { return x / (1.f + __expf(-x)); }
__device__ __forceinline__ float geluf(float x)  { return 0.5f * x * (1.f + erff(x * 0.70710678118654752f)); }
__device__ __forceinline__ float softplusf(float x) { return (x > 20.f) ? x : log1pf(__expf(x)); }
__device__ __forceinline__ float bf2f(short u) {
    union { unsigned int i; float f; } cv; cv.i = ((unsigned int)(unsigned short)u) << 16; return cv.f;
}
__device__ __forceinline__ short f2bf_bits(float v) {
    __hip_bfloat16 h = __float2bfloat16(v);
    return *(short*)&h;
}

// ---------------- weight fp32 -> bf16 conversion ----------------
#define WSZ0 147456  // in_proj_w 768*192
#define WSZ1 16896   // x_proj_w 44*384
#define WSZ2 73728   // out_proj_w 192*384
#define WSZ3 147456  // mlp_w1 768*192
#define WSZ4 147456  // mlp_w2 192*768
__global__ __launch_bounds__(256) void cvt_weights(const float* __restrict__ w0, const float* __restrict__ w1,
                                                   const float* __restrict__ w2, const float* __restrict__ w3,
                                                   const float* __restrict__ w4,
                                                   __hip_bfloat16* __restrict__ o0, __hip_bfloat16* __restrict__ o1,
                                                   __hip_bfloat16* __restrict__ o2, __hip_bfloat16* __restrict__ o3,
                                                   __hip_bfloat16* __restrict__ o4) {
    int i = blockIdx.x * 256 + threadIdx.x;
    if (i < WSZ0) { o0[i] = __float2bfloat16(w0[i]); return; } i -= WSZ0;
    if (i < WSZ1) { o1[i] = __float2bfloat16(w1[i]); return; } i -= WSZ1;
    if (i < WSZ2) { o2[i] = __float2bfloat16(w2[i]); return; } i -= WSZ2;
    if (i < WSZ3) { o3[i] = __float2bfloat16(w3[i]); return; } i -= WSZ3;
    if (i < WSZ4) { o4[i] = __float2bfloat16(w4[i]); }
}

// ---------------- LayerNorm over C, LDS-tiled, coalesced ----------------
// block: 256 threads, 64 tokens (one b, 64 consecutive hw). grid (49, BATCH).
__global__ __launch_bounds__(256) void ln_kernel(const float* __restrict__ x,
                                                 const float* __restrict__ g,
                                                 const float* __restrict__ bta,
                                                 __hip_bfloat16* __restrict__ out) {
    __shared__ float tile[CCH * 65];   // [c][w], stride 65 breaks bank conflicts
    __shared__ float gs[CCH], bs[CCH];
    int t = threadIdx.x;
    int b = blockIdx.y, hw0 = blockIdx.x * 64;
    const float* xb = x + (size_t)b * CCH * LSEQ + hw0;
#pragma unroll 8
    for (int k = 0; k < 48; k++) {
        int idx = k * 256 + t;           // 0..12287
        int c = idx >> 6, w = idx & 63;
        tile[c * 65 + w] = xb[(size_t)c * LSEQ + w];
    }
    if (t < CCH) { gs[t] = g[t]; bs[t] = bta[t]; }
    __syncthreads();
    int lane = t & 63, wave = t >> 6;
    int tk = lane & 15, p = lane >> 4;   // token-in-wave, channel quarter
    int tok = wave * 16 + tk;
    float s = 0.f, s2 = 0.f;
#pragma unroll 8
    for (int i = 0; i < 48; i++) {
        float v = tile[(p * 48 + i) * 65 + tok];
        s += v; s2 += v * v;
    }
    s += __shfl_xor(s, 16); s2 += __shfl_xor(s2, 16);
    s += __shfl_xor(s, 32); s2 += __shfl_xor(s2, 32);
    float mean = s * (1.f / CCH);
    float rstd = rsqrtf(s2 * (1.f / CCH) - mean * mean + 1e-5f);
    // redistribute: lane writes token j=lane>>2 (this wave), quarter q=lane&3
    int j = lane >> 2, q = lane & 3;
    float mj = __shfl(mean, j);
    float rj = __shfl(rstd, j);
    int wtok = wave * 16 + j;
    __hip_bfloat16* op = out + (size_t)(b * LSEQ + hw0 + wtok) * CCH + q * 48;
#pragma unroll
    for (int kk = 0; kk < 6; kk++) {
        short8 pk;
#pragma unroll
        for (int e = 0; e < 8; e++) {
            int c = q * 48 + kk * 8 + e;
            float v = (tile[c * 65 + wtok] - mj) * rj * gs[c] + bs[c];
            pk[e] = f2bf_bits(v);
        }
        *(short8*)(op + kk * 8) = pk;
    }
}

// ---------------- bf16 MFMA GEMM: C[M=NTOK, N] = A[M,K] * W[N,K]^T ----------------
// EPI: 0 = plain store, 2 = +bias+GELU, 3 = +res NCHW transposed store, 4 = +bias+res NCHW
template<int EPI, typename OutT>
__global__ __launch_bounds__(256) void gemm_mfma(const __hip_bfloat16* __restrict__ A,
                                                 const __hip_bfloat16* __restrict__ W,
                                                 const float* __restrict__ bias,
                                                 const float* __restrict__ res,
                                                 OutT* __restrict__ Cout,
                                                 int N, int K) {
    __shared__ __align__(16) __hip_bfloat16 As[128 * 40];
    __shared__ __align__(16) __hip_bfloat16 Bs[128 * 40];
    int tid = threadIdx.x;
    int bm = blockIdx.y * 128, bn = blockIdx.x * 128;
    int wave = tid >> 6, lane = tid & 63;
    int wm = (wave >> 1) * 64, wn = (wave & 1) * 64;
    int lm = lane & 15, quad = lane >> 4;
    floatx4 acc[4][4] = {};
    int lrow = tid >> 2;
    int lcol = (tid & 3) * 8;
    for (int k0 = 0; k0 < K; k0 += 32) {
#pragma unroll
        for (int p = 0; p < 2; p++) {
            int row = lrow + p * 64;
            *(short8*)&As[row * 40 + lcol] = *(const short8*)(A + (size_t)(bm + row) * K + k0 + lcol);
            int n = bn + row;
            short8 bv = {0,0,0,0,0,0,0,0};
            if (n < N) bv = *(const short8*)(W + (size_t)n * K + k0 + lcol);
            *(short8*)&Bs[row * 40 + lcol] = bv;
        }
        __syncthreads();
        short8 a[4], b[4];
#pragma unroll
        for (int i = 0; i < 4; i++) a[i] = *(const short8*)&As[(wm + i * 16 + lm) * 40 + quad * 8];
#pragma unroll
        for (int j = 0; j < 4; j++) b[j] = *(const short8*)&Bs[(wn + j * 16 + lm) * 40 + quad * 8];
#pragma unroll
        for (int i = 0; i < 4; i++)
#pragma unroll
            for (int j = 0; j < 4; j++)
                acc[i][j] = __builtin_amdgcn_mfma_f32_16x16x32_bf16(a[i], b[j], acc[i][j], 0, 0, 0);
        __syncthreads();
    }
#pragma unroll
    for (int j = 0; j < 4; j++) {
        int n = bn + wn + j * 16 + lm;
        if (n >= N) continue;
        float bv = (EPI == 2 || EPI == 4) ? bias[n] : 0.f;
#pragma unroll
        for (int i = 0; i < 4; i++) {
            int mrow = bm + wm + i * 16 + quad * 4;
            if (EPI == 3 || EPI == 4) {
                int bb = mrow / LSEQ;
                int l0 = mrow % LSEQ;
                size_t oidx = ((size_t)(bb * CCH + n)) * LSEQ + l0;
                float4 xr = *(const float4*)(res + oidx);
                float4 v;
                v.x = acc[i][j][0] + bv + xr.x;
                v.y = acc[i][j][1] + bv + xr.y;
                v.z = acc[i][j][2] + bv + xr.z;
                v.w = acc[i][j][3] + bv + xr.w;
                *(float4*)((float*)Cout + oidx) = v;
            } else {
#pragma unroll
                for (int r = 0; r < 4; r++) {
                    float v = acc[i][j][r];
                    if (EPI == 2) { v += bv; v = geluf(v); }
                    Cout[(size_t)(mrow + r) * N + n] = (OutT)v;
                }
            }
        }
    }
}

// ---------------- fp32 GEMM for dt_proj (K=12) + softplus ----------------
__global__ __launch_bounds__(256) void gemm_nt_dt(const float* __restrict__ A,
                                                  const float* __restrict__ Wt,
                                                  const float* __restrict__ bias,
                                                  float* __restrict__ Cout) {
    __shared__ float As[16][64 + 1];
    __shared__ float Ws[16][64 + 1];
    const int N = DIN, K = DTR;
    int tid = threadIdx.x;
    int bm = blockIdx.y * 64;
    int bn = blockIdx.x * 64;
    int lr = tid >> 4;
    int lk = tid & 15;
    int tm = (tid >> 4) << 2;
    int tn = (tid & 15) << 2;
    float acc[4][4] = {};
#pragma unroll
    for (int p = 0; p < 4; p++) {
        int m = bm + lr + 16 * p;
        As[lk][lr + 16 * p] = (lk < K) ? A[(size_t)m * XDM + lk] : 0.f;
        int n = bn + lr + 16 * p;
        Ws[lk][lr + 16 * p] = (lk < K) ? Wt[(size_t)n * K + lk] : 0.f;
    }
    __syncthreads();
#pragma unroll
    for (int kk = 0; kk < 12; kk++) {
        float a[4], w[4];
#pragma unroll
        for (int i = 0; i < 4; i++) a[i] = As[kk][tm + i];
#pragma unroll
        for (int j = 0; j < 4; j++) w[j] = Ws[kk][tn + j];
#pragma unroll
        for (int i = 0; i < 4; i++)
#pragma unroll
            for (int j = 0; j < 4; j++)
                acc[i][j] += a[i] * w[j];
    }
#pragma unroll
    for (int i = 0; i < 4; i++) {
        int m = bm + tm + i;
#pragma unroll
        for (int j = 0; j < 4; j++) {
            int n = bn + tn + j;
            Cout[(size_t)m * N + n] = softplusf(acc[i][j] + bias[n]);
        }
    }
}

// ---------------- causal depthwise conv1d (k=3) + SiLU, 4 d's/thread, bf16 in ----------------
__global__ __launch_bounds__(256) void conv1d_silu(const __hip_bfloat16* __restrict__ xz,
                                                   const float* __restrict__ w,
                                                   const float* __restrict__ bias,
                                                   float* __restrict__ out,
                                                   __hip_bfloat16* __restrict__ out_bf) {
    int idx = blockIdx.x * 256 + threadIdx.x;
    if (idx >= NTOK * (DIN / 4)) return;
    int m = idx / (DIN / 4), d = (idx % (DIN / 4)) * 4;
    int l = m % LSEQ;
    short4v cur = *(const short4v*)&xz[(size_t)m * (2 * DIN) + d];
    short4v p1 = {0,0,0,0}, p2 = {0,0,0,0};
    if (l >= 1) p1 = *(const short4v*)&xz[(size_t)(m - 1) * (2 * DIN) + d];
    if (l >= 2) p2 = *(const short4v*)&xz[(size_t)(m - 2) * (2 * DIN) + d];
    float4 bv = *(const float4*)&bias[d];
    float ob[4];
    float4 of;
#pragma unroll
    for (int jj = 0; jj < 4; jj++) {
        float w0 = w[(d + jj) * 3 + 0], w1 = w[(d + jj) * 3 + 1], w2 = w[(d + jj) * 3 + 2];
        float acc = ((const float*)&bv)[jj] + w2 * bf2f(cur[jj]) + w1 * bf2f(p1[jj]) + w0 * bf2f(p2[jj]);
        float v = siluf(acc);
        ((float*)&of)[jj] = v;
        ob[jj] = v;
    }
    *(float4*)&out[(size_t)m * DIN + d] = of;
    short4v obv = { f2bf_bits(ob[0]), f2bf_bits(ob[1]), f2bf_bits(ob[2]), f2bf_bits(ob[3]) };
    *(short4v*)&out_bf[(size_t)m * DIN + d] = obv;
}

// ---------------- chunked selective scan, 2 threads/d (8 states each) ----------------
// block 256 threads: d = d0 + (t>>1), half = t&1; grid (NC, DIN/128, BATCH)
__global__ __launch_bounds__(256) void scan_phase1(const float* __restrict__ delta,
                                                   const float* __restrict__ xm,
                                                   const float* __restrict__ xdbl,
                                                   const float* __restrict__ A_log,
                                                   float* __restrict__ Pbuf,
                                                   float* __restrict__ Qbuf) {
    __shared__ float b_s[CL][16];
    int t = threadIdx.x;
    int b = blockIdx.z, c = blockIdx.x, d0 = blockIdx.y * 128;
    int m0 = b * LSEQ + c * CL;
    {   // stage B: CL x 16 floats = 512, 256 thr x float2
        int i = t >> 3, q = (t & 7) * 2;
        *(float2*)&b_s[i][q] = *(const float2*)&xdbl[(size_t)(m0 + i) * XDM + DTR + q];
    }
    __syncthreads();
    int d = d0 + (t >> 1), half = t & 1;
    float An[8];
#pragma unroll
    for (int n4 = 0; n4 < 2; n4++) {
        float4 a = *(const float4*)&A_log[d * DST + half * 8 + n4 * 4];
        An[n4 * 4 + 0] = -__expf(a.x);
        An[n4 * 4 + 1] = -__expf(a.y);
        An[n4 * 4 + 2] = -__expf(a.z);
        An[n4 * 4 + 3] = -__expf(a.w);
    }
    float Q[8];
#pragma unroll
    for (int n = 0; n < 8; n++) Q[n] = 0.f;
    float s = 0.f;
    const float* dp = delta + (size_t)m0 * DIN + d;
    const float* xp = xm    + (size_t)m0 * DIN + d;
#pragma unroll 4
    for (int i = 0; i < CL; i++) {
        float dlt = dp[(size_t)i * DIN];
        float xv  = xp[(size_t)i * DIN];
        s += dlt;
        float tt = dlt * xv;
#pragma unroll
        for (int n = 0; n < 8; n++) {
            float dA = __expf(dlt * An[n]);
            Q[n] = dA * Q[n] + tt * b_s[i][half * 8 + n];
        }
    }
    size_t o = ((size_t)(b * NC + c) * DIN + d) * DST + half * 8;
#pragma unroll
    for (int n4 = 0; n4 < 2; n4++) {
        float4 Pv, Qv;
        Pv.x = __expf(An[n4 * 4 + 0] * s);
        Pv.y = __expf(An[n4 * 4 + 1] * s);
        Pv.z = __expf(An[n4 * 4 + 2] * s);
        Pv.w = __expf(An[n4 * 4 + 3] * s);
        Qv.x = Q[n4 * 4 + 0]; Qv.y = Q[n4 * 4 + 1];
        Qv.z = Q[n4 * 4 + 2]; Qv.w = Q[n4 * 4 + 3];
        *(float4*)&Pbuf[o + n4 * 4] = Pv;
        *(float4*)&Qbuf[o + n4 * 4] = Qv;
    }
}

// phase 2: sequential combine over chunks (NC steps)
__global__ __launch_bounds__(256) void scan_phase2(const float* __restrict__ Pbuf,
                                                   const float* __restrict__ Qbuf,
                                                   float* __restrict__ Hin) {
    int t = blockIdx.x * 256 + threadIdx.x;
    if (t >= BATCH * DIN * DST) return;
    int b = t / (DIN * DST);
    int rem = t % (DIN * DST);
    float h = 0.f;
#pragma unroll 7
    for (int c = 0; c < NC; c++) {
        size_t o = (size_t)(b * NC + c) * (DIN * DST) + rem;
        Hin[o] = h;
        h = Pbuf[o] * h + Qbuf[o];
    }
}

// phase 3: re-scan from true h_in, 2 threads/d, y combined via shfl_xor(1)
__global__ __launch_bounds__(256) void scan_phase3(const float* __restrict__ delta,
                                                   const float* __restrict__ xm,
                                                   const float* __restrict__ xdbl,
                                                   const __hip_bfloat16* __restrict__ xz,
                                                   const float* __restrict__ A_log,
                                                   const float* __restrict__ Dskip,
                                                   const float* __restrict__ Hin,
                                                   __hip_bfloat16* __restrict__ ybuf) {
    __shared__ float bc_s[CL][32];
    int t = threadIdx.x;
    int b = blockIdx.z, c = blockIdx.x, d0 = blockIdx.y * 128;
    int m0 = b * LSEQ + c * CL;
    {   // stage B|C: CL x 32 floats = 1024, 256 thr x float4
        int i = t >> 3, q = (t & 7) * 4;
        *(float4*)&bc_s[i][q] = *(const float4*)&xdbl[(size_t)(m0 + i) * XDM + DTR + q];
    }
    __syncthreads();
    int d = d0 + (t >> 1), half = t & 1;
    float An[8];
#pragma unroll
    for (int n4 = 0; n4 < 2; n4++) {
        float4 a = *(const float4*)&A_log[d * DST + half * 8 + n4 * 4];
        An[n4 * 4 + 0] = -__expf(a.x);
        An[n4 * 4 + 1] = -__expf(a.y);
        An[n4 * 4 + 2] = -__expf(a.z);
        An[n4 * 4 + 3] = -__expf(a.w);
    }
    float h[8];
    size_t o = ((size_t)(b * NC + c) * DIN + d) * DST + half * 8;
    {
        float4 h0 = *(const float4*)&Hin[o];
        float4 h1 = *(const float4*)&Hin[o + 4];
        h[0] = h0.x; h[1] = h0.y; h[2] = h0.z; h[3] = h0.w;
        h[4] = h1.x; h[5] = h1.y; h[6] = h1.z; h[7] = h1.w;
    }
    float Dv = Dskip[d];
    const float* dp = delta + (size_t)m0 * DIN + d;
    const float* xp = xm    + (size_t)m0 * DIN + d;
    const __hip_bfloat16* zp = xz + (size_t)m0 * (2 * DIN) + DIN + d;
    __hip_bfloat16* yo = ybuf + (size_t)m0 * DIN + d;
#pragma unroll 2
    for (int i = 0; i < CL; i++) {
        float dlt = dp[(size_t)i * DIN];
        float xv  = xp[(size_t)i * DIN];
        float tt = dlt * xv;
        float y = 0.f;
#pragma unroll
        for (int n = 0; n < 8; n++) {
            float dA = __expf(dlt * An[n]);
            h[n] = dA * h[n] + tt * bc_s[i][half * 8 + n];
            y += h[n] * bc_s[i][16 + half * 8 + n];
        }
        y += __shfl_xor(y, 1);
        if (half == 0) {
            float zv = bf2f(*(const short*)(zp + (size_t)i * (2 * DIN)));
            yo[(size_t)i * DIN] = __float2bfloat16((y + xv * Dv) * siluf(zv));
        }
    }
}

// ---------------- depthwise 3x3 conv + BN + GELU + residual ----------------
__global__ __launch_bounds__(256) void dwconv_bn_gelu(const float* __restrict__ x1,
                                                      const float* __restrict__ wdw,
                                                      const float* __restrict__ bn_g,
                                                      const float* __restrict__ bn_b,
                                                      const float* __restrict__ bn_mean,
                                                      const float* __restrict__ bn_var,
                                                      float* __restrict__ x2) {
    int idx = blockIdx.x * 256 + threadIdx.x;
    if (idx >= NTOK * CCH) return;
    int w = idx % WW; int tmp = idx / WW;
    int h = tmp % HH; tmp /= HH;
    int c = tmp % CCH; int b = tmp / CCH;
    const float* base = x1 + ((size_t)(b * CCH + c)) * LSEQ;
    float acc = 0.f;
#pragma unroll
    for (int dh = -1; dh <= 1; dh++) {
        int hh = h + dh;
        if (hh < 0 || hh >= HH) continue;
#pragma unroll
        for (int dw = -1; dw <= 1; dw++) {
            int wcol = w + dw;
            if (wcol < 0 || wcol >= WW) continue;
            acc += wdw[c * 9 + (dh + 1) * 3 + (dw + 1)] * base[hh * WW + wcol];
        }
    }
    float bn = (acc - bn_mean[c]) * rsqrtf(bn_var[c] + 1e-5f) * bn_g[c] + bn_b[c];
    x2[idx] = x1[idx] + geluf(bn);
}

extern "C" void kernel_launch(void* const* d_in, const int* in_sizes, int n_in,
                              void* d_out, int out_size, void* d_ws, size_t ws_size,
                              hipStream_t stream) {
    const float* x         = (const float*)d_in[0];
    const float* ln1_g     = (const float*)d_in[1];
    const float* ln1_b     = (const float*)d_in[2];
    const float* in_proj_w = (const float*)d_in[3];
    const float* conv_w    = (const float*)d_in[4];
    const float* conv_b    = (const float*)d_in[5];
    const float* x_proj_w  = (const float*)d_in[6];
    const float* dt_proj_w = (const float*)d_in[7];
    const float* dt_proj_b = (const float*)d_in[8];
    const float* A_log     = (const float*)d_in[9];
    const float* Dskip     = (const float*)d_in[10];
    const float* out_proj_w= (const float*)d_in[11];
    const float* dw_w      = (const float*)d_in[12];
    const float* bn_g      = (const float*)d_in[13];
    const float* bn_b      = (const float*)d_in[14];
    const float* bn_mean   = (const float*)d_in[15];
    const float* bn_var    = (const float*)d_in[16];
    const float* ln2_g     = (const float*)d_in[17];
    const float* ln2_b     = (const float*)d_in[18];
    const float* mlp_w1    = (const float*)d_in[19];
    const float* mlp_b1    = (const float*)d_in[20];
    const float* mlp_w2    = (const float*)d_in[21];
    const float* mlp_b2    = (const float*)d_in[22];
    float* out = (float*)d_out;

    // ---- workspace layout ----
    float* ws = (float*)d_ws;
    __hip_bfloat16* xz_bf = (__hip_bfloat16*)ws;          // NTOK*768 bf16
    float* xm_act = (float*)(xz_bf + (size_t)NTOK * 768); // NTOK*384 f32
    float* deltab = xm_act + (size_t)NTOK * DIN;          // NTOK*384 f32 (aliased by hidden_bf later)
    float* xdbl   = deltab + (size_t)NTOK * DIN;          // NTOK*44 f32
    float* mo     = xdbl   + (size_t)NTOK * XDM;          // NTOK*192 f32 (scan Pbuf)
    float* x1     = mo     + (size_t)NTOK * CCH;          // NTOK*192 f32 (scan Qbuf, then x1 NCHW)
    float* x2     = x1     + (size_t)NTOK * CCH;          // NTOK*192 f32 (scan Hin, then x2 NCHW)
    __hip_bfloat16* tokens_bf = (__hip_bfloat16*)(x2 + (size_t)NTOK * CCH);       // NTOK*192 bf16
    __hip_bfloat16* xm_bf     = tokens_bf + (size_t)NTOK * CCH;                   // NTOK*384 bf16
    __hip_bfloat16* ybuf_bf   = xm_bf + (size_t)NTOK * DIN;                       // NTOK*384 bf16
    __hip_bfloat16* wpool     = ybuf_bf + (size_t)NTOK * DIN;
    __hip_bfloat16* in_w_bf   = wpool;
    __hip_bfloat16* xp_w_bf   = in_w_bf + WSZ0;
    __hip_bfloat16* op_w_bf   = xp_w_bf + WSZ1;
    __hip_bfloat16* w1_bf     = op_w_bf + WSZ2;
    __hip_bfloat16* w2_bf     = w1_bf + WSZ3;
    float* Pbuf = mo;
    float* Qbuf = x1;
    float* Hin  = x2;
    __hip_bfloat16* hidden_bf = (__hip_bfloat16*)deltab;  // mlp1 out aliases deltab

    // 0) weights -> bf16
    cvt_weights<<<(WSZ0 + WSZ1 + WSZ2 + WSZ3 + WSZ4 + 255) / 256, 256, 0, stream>>>(
        in_proj_w, x_proj_w, out_proj_w, mlp_w1, mlp_w2,
        in_w_bf, xp_w_bf, op_w_bf, w1_bf, w2_bf);
    // 1) LN1 -> tokens_bf
    ln_kernel<<<dim3(LSEQ / 64, BATCH), 256, 0, stream>>>(x, ln1_g, ln1_b, tokens_bf);
    // 2) in_proj (MFMA) -> xz bf16
    gemm_mfma<0, __hip_bfloat16><<<dim3(768 / 128, NTOK / 128), 256, 0, stream>>>(tokens_bf, in_w_bf, nullptr, nullptr, xz_bf, 768, CCH);
    // 3) conv1d + silu -> xm_act f32 + xm_bf
    conv1d_silu<<<(NTOK * (DIN / 4) + 255) / 256, 256, 0, stream>>>(xz_bf, conv_w, conv_b, xm_act, xm_bf);
    // 4) x_proj (MFMA, N=44) -> xdbl
    gemm_mfma<0, float><<<dim3(1, NTOK / 128), 256, 0, stream>>>(xm_bf, xp_w_bf, nullptr, nullptr, xdbl, XDM, DIN);
    // 5) dt_proj + softplus -> deltab
    gemm_nt_dt<<<dim3(DIN / 64, NTOK / 64), 256, 0, stream>>>(xdbl, dt_proj_w, dt_proj_b, deltab);
    // 6) chunked selective scan -> ybuf_bf
    scan_phase1<<<dim3(NC, DIN / 128, BATCH), 256, 0, stream>>>(deltab, xm_act, xdbl, A_log, Pbuf, Qbuf);
    scan_phase2<<<(BATCH * DIN * DST + 255) / 256, 256, 0, stream>>>(Pbuf, Qbuf, Hin);
    scan_phase3<<<dim3(NC, DIN / 128, BATCH), 256, 0, stream>>>(deltab, xm_act, xdbl, xz_bf, A_log, Dskip, Hin, ybuf_bf);
    // 7) out_proj (MFMA) fused residual-add + NCHW transpose store -> x1
    gemm_mfma<3, float><<<dim3(2, NTOK / 128), 256, 0, stream>>>(ybuf_bf, op_w_bf, nullptr, x, x1, CCH, DIN);
    // 8) x2 = x1 + gelu(bn(dwconv3x3(x1)))
    dwconv_bn_gelu<<<(NTOK * CCH + 255) / 256, 256, 0, stream>>>(x1, dw_w, bn_g, bn_b, bn_mean, bn_var, x2);
    // 9) LN2 -> tokens_bf
    ln_kernel<<<dim3(LSEQ / 64, BATCH), 256, 0, stream>>>(x2, ln2_g, ln2_b, tokens_bf);
    // 10) mlp1 (MFMA) + bias + gelu -> hidden_bf
    gemm_mfma<2, __hip_bfloat16><<<dim3(768 / 128, NTOK / 128), 256, 0, stream>>>(tokens_bf, w1_bf, mlp_b1, nullptr, hidden_bf, 768, CCH);
    // 11) mlp2 (MFMA) fused +b2 +x2 residual, NCHW store -> out
    gemm_mfma<4, float><<<dim3(2, NTOK / 128), 256, 0, stream>>>(hidden_bf, w2_bf, mlp_b2, x2, out, CCH, 4 * CCH);
}